// Round 13
// baseline (2113.643 us; speedup 1.0000x reference)
//
#include <hip/hip_runtime.h>

#define H 128
#define Nn 100000
#define Ee 250000
#define N5c 20000
#define N6c 30000
#define Gg 512
#define Ll 3
#define AF 9
#define AV 64
#define BF 3
#define BV 8
#define BN_EPS 1e-5f

typedef __bf16 v8bf __attribute__((ext_vector_type(8)));
typedef float v4f __attribute__((ext_vector_type(4)));

struct bfpair { __bf16 h, l; };
__device__ inline bfpair split2(float v) {
    bfpair r;
    r.h = (__bf16)v;
    r.l = (__bf16)(v - (float)r.h);
    return r;
}

// ---------------- init / embedding kernels ----------------

__global__ void k_atom_enc(const int* __restrict__ xa, const float* __restrict__ emb,
                           __bf16* __restrict__ x) {
    int idx = blockIdx.x * blockDim.x + threadIdx.x;
    if (idx >= Nn * H) return;
    int n = idx >> 7, h = idx & 127;
    float s = 0.f;
#pragma unroll
    for (int f = 0; f < AF; ++f) {
        int a = xa[n * AF + f];
        s += emb[(f * AV + a) * H + h];
    }
    x[idx] = (__bf16)s;
}

__global__ void k_cyc_init(const int* __restrict__ xc, const float* __restrict__ emb,
                           __bf16* __restrict__ xo, int M) {
    int idx = blockIdx.x * blockDim.x + threadIdx.x;
    if (idx >= M * H) return;
    int m = idx >> 7, h = idx & 127;
    xo[idx] = (__bf16)emb[xc[m] * H + h];
}

// weight pre-split: (L,K,N) fp32 row-major -> per-layer transposed [n][k] bf16
__global__ void k_split(const float* __restrict__ src, __bf16* __restrict__ dh,
                        int L, int K, int N) {
    int idx = blockIdx.x * blockDim.x + threadIdx.x;
    int tot = L * K * N;
    if (idx >= tot) return;
    int l = idx / (K * N);
    int r = idx - l * (K * N);
    int k = r / N;
    int n = r - k * N;
    size_t d = (size_t)l * K * N + (size_t)n * K + k;
    dh[d] = (__bf16)src[idx];
}

// ---------------- CSR build helpers ----------------

__global__ void k_degi(const int* __restrict__ row, int* __restrict__ deg, int M) {
    int m = blockIdx.x * blockDim.x + threadIdx.x;
    if (m >= M) return;
    atomicAdd(&deg[row[m]], 1);
}

__global__ void k_scan1(const int* __restrict__ deg, int* __restrict__ rp,
                        int* __restrict__ bsum, int n) {
    __shared__ int s[256];
    int tid = threadIdx.x;
    int base = blockIdx.x * 1024 + tid * 4;
    int v0 = (base < n) ? deg[base] : 0;
    int v1 = (base + 1 < n) ? deg[base + 1] : 0;
    int v2 = (base + 2 < n) ? deg[base + 2] : 0;
    int v3 = (base + 3 < n) ? deg[base + 3] : 0;
    int tsum = v0 + v1 + v2 + v3;
    s[tid] = tsum;
    __syncthreads();
    for (int off = 1; off < 256; off <<= 1) {
        int u = (tid >= off) ? s[tid - off] : 0;
        __syncthreads();
        s[tid] += u;
        __syncthreads();
    }
    int exc = s[tid] - tsum;
    if (base < n) rp[base] = exc;
    if (base + 1 < n) rp[base + 1] = exc + v0;
    if (base + 2 < n) rp[base + 2] = exc + v0 + v1;
    if (base + 3 < n) rp[base + 3] = exc + v0 + v1 + v2;
    if (tid == 255) bsum[blockIdx.x] = s[255];
}

__global__ void k_scan2(const int* __restrict__ bsum, int* __restrict__ boff,
                        int* __restrict__ rp, int nb, int n) {
    __shared__ int s[128];
    int tid = threadIdx.x;
    int v = (tid < nb) ? bsum[tid] : 0;
    s[tid] = v;
    __syncthreads();
    for (int off = 1; off < 128; off <<= 1) {
        int u = (tid >= off) ? s[tid - off] : 0;
        __syncthreads();
        s[tid] += u;
        __syncthreads();
    }
    if (tid < nb) boff[tid] = s[tid] - v;
    if (tid == 127) rp[n] = s[127];
}

__global__ void k_scan3(int* __restrict__ rp, const int* __restrict__ boff, int n) {
    int idx = blockIdx.x * blockDim.x + threadIdx.x;
    if (idx < n) rp[idx] += boff[idx >> 10];
}

__global__ void k_fill(const int* __restrict__ ei, const int* __restrict__ eattr,
                       int* __restrict__ woff, unsigned int* __restrict__ elist) {
    int e = blockIdx.x * blockDim.x + threadIdx.x;
    if (e >= Ee) return;
    int src = ei[e], dst = ei[Ee + e];
    int code = eattr[e * BF + 0] * 64 + eattr[e * BF + 1] * 8 + eattr[e * BF + 2];
    int p = atomicAdd(&woff[dst], 1);
    elist[p] = ((unsigned int)code << 17) | (unsigned int)src;
}

__global__ void k_fill_idx(const int* __restrict__ row, int* __restrict__ woff,
                           int* __restrict__ cidx, int M) {
    int m = blockIdx.x * blockDim.x + threadIdx.x;
    if (m >= M) return;
    int p = atomicAdd(&woff[row[m]], 1);
    cidx[p] = m;
}

__global__ void k_inv_int(const int* __restrict__ deg, float* __restrict__ rscale) {
    int r = blockIdx.x * blockDim.x + threadIdx.x;
    if (r >= Nn) return;
    rscale[r] = 1.f / fmaxf((float)deg[r], 1.f);
}

__global__ void k_ebank(const float* __restrict__ bemb, float* __restrict__ ebank) {
    int idx = blockIdx.x * blockDim.x + threadIdx.x;
    if (idx >= 512 * H) return;
    int code = idx >> 7, h = idx & 127;
    int f0 = code >> 6, f1 = (code >> 3) & 7, f2 = code & 7;
    ebank[idx] = bemb[(0 * BV + f0) * H + h] + bemb[(1 * BV + f1) * H + h]
               + bemb[(2 * BV + f2) * H + h];
}

// GINE aggregation, gather form (bf16 activations, fp32 accumulate)
__global__ __launch_bounds__(256) void k_agg_csr(
    const __bf16* __restrict__ x, const int* __restrict__ rowptr,
    const unsigned int* __restrict__ elist, const float* __restrict__ ebank,
    const float* __restrict__ eps, int layer, __bf16* __restrict__ agg)
{
    int a = blockIdx.x * 2 + (threadIdx.x >> 7);
    int h = threadIdx.x & 127;
    float acc = (1.f + eps[layer]) * (float)x[(size_t)a * H + h];
    int j0 = rowptr[a], j1 = rowptr[a + 1];
    for (int j = j0; j < j1; ++j) {
        unsigned int u = elist[j];
        int src = u & 0x1FFFF;
        int code = u >> 17;
        acc += fmaxf((float)x[(size_t)src * H + h] + ebank[code * H + h], 0.f);
    }
    agg[(size_t)a * H + h] = (__bf16)acc;
}

// CSR mean-gather: out[a] = rscale[a] * sum_j xc[cidx[j]]  (bf16, vectorized)
__global__ __launch_bounds__(256) void k_gmean(
    const __bf16* __restrict__ xc, const int* __restrict__ grp,
    const int* __restrict__ gcol, const float* __restrict__ rscale,
    __bf16* __restrict__ outg)
{
    int idx = blockIdx.x * blockDim.x + threadIdx.x;
    if (idx >= Nn * 16) return;
    int a = idx >> 4, c8 = (idx & 15) * 8;
    int j0 = grp[a], j1 = grp[a + 1];
    float acc[8] = {0.f, 0.f, 0.f, 0.f, 0.f, 0.f, 0.f, 0.f};
    for (int j = j0; j < j1; ++j) {
        v8bf g = *(const v8bf*)(xc + (size_t)gcol[j] * H + c8);
#pragma unroll
        for (int i = 0; i < 8; ++i) acc[i] += (float)g[i];
    }
    float s = rscale[a];
    v8bf o;
#pragma unroll
    for (int i = 0; i < 8; ++i) o[i] = (__bf16)(acc[i] * s);
    *(v8bf*)(outg + (size_t)a * H + c8) = o;
}

// ---------------- MFMA GEMM: 64-row blocks, full-K A register preload -------------
// NKT = K/32 (4 for K=128, 12 for K=384). 4 waves x 16 rows. B chunked in LDS with
// register prefetch. A-modes: pathk (cyclic conv, mtile multiple of pathk, in-place
// safe via pre-epilogue barrier); rowidx; else direct (stride K).
// epi: 0 = bf16 out (+bf16 res/relu); 2 = bf16 out write + column stats.
// bnmode: 1 = folded BN+relu on A (K==128); 2 = folded BN+relu on res read.

template <int NKT>
__global__ __launch_bounds__(256) void k_mgemm(
    const __bf16* __restrict__ A, const __bf16* __restrict__ Bth,
    const float* __restrict__ bias, const __bf16* __restrict__ res,
    __bf16* __restrict__ out, const int* __restrict__ rowidx,
    float* __restrict__ stats,
    const float* __restrict__ bnstats, const float* __restrict__ bng,
    const float* __restrict__ bnb,
    int M, int Ncol, int pathk, int mtile, int relu_flag, int epi, int bnmode)
{
    const int K = NKT * 32;
    __shared__ __bf16 Bs[2][128][40];
    __shared__ float sS[128], sQ[128];
    __shared__ float scB[128], shB[128];

    int t = threadIdx.x;
    int m0 = blockIdx.x * mtile;
    int n0 = blockIdx.y * 128;
    int lane = t & 63, q = lane >> 4, lr = lane & 15;
    int w = t >> 6;

    if (bnmode && t < 128) {
        float mean = bnstats[t] * (1.f / (float)Nn);
        float var = bnstats[128 + t] * (1.f / (float)Nn) - mean * mean;
        float s = bng[t] * rsqrtf(var + BN_EPS);
        scB[t] = s;
        shB[t] = bnb[t] - mean * s;
    }

    // upfront A fragment preload (this wave's 16 rows; lane lr = row, q = k-quad)
    int rloc = w * 16 + lr;
    int gm = m0 + rloc;
    bool rvalid = (rloc < mtile) && (gm < M);
    v8bf afrag[NKT];
    {
        const __bf16* base = A;
        int cycb = 0, pm = 0;
        if (rvalid) {
            if (pathk) {
                int cyc = gm / pathk;
                cycb = cyc * pathk;
                pm = gm - cycb;
            } else if (rowidx) {
                base = A + (size_t)rowidx[gm] * H;
            } else {
                base = A + (size_t)gm * K;
            }
        }
#pragma unroll
        for (int kt = 0; kt < NKT; ++kt) {
            v8bf hv = {};
            if (rvalid) {
                if (pathk) {
                    int sel = kt >> 2;  // neighbor 0,1,2 per 128-K block
                    int pp = pm + sel - 1;
                    if (pp < 0) pp += pathk;
                    if (pp >= pathk) pp -= pathk;
                    hv = *(const v8bf*)(A + (size_t)(cycb + pp) * H +
                                        ((kt * 32) & 127) + q * 8);
                } else {
                    hv = *(const v8bf*)(base + kt * 32 + q * 8);
                }
            }
            afrag[kt] = hv;
        }
    }
    if (bnmode == 1) {
        __syncthreads();  // scB ready
        if (rvalid) {
#pragma unroll
            for (int kt = 0; kt < NKT; ++kt) {
                int kb = kt * 32 + q * 8;
#pragma unroll
                for (int i = 0; i < 8; ++i)
                    afrag[kt][i] =
                        (__bf16)fmaxf((float)afrag[kt][i] * scB[kb + i] + shB[kb + i], 0.f);
            }
        }
    }

    v4f acc[8] = {};
    int bn = t & 127;
    int ks = t >> 7;

    v8bf vb[2][2];
    auto loadBreg = [&](int c) {
#pragma unroll
        for (int s2 = 0; s2 < 2; ++s2) {
            const __bf16* bp = Bth + (size_t)(n0 + bn) * K + (c << 6) + s2 * 32 + ks * 16;
            vb[s2][0] = *(const v8bf*)bp;
            vb[s2][1] = *(const v8bf*)(bp + 8);
        }
    };
    loadBreg(0);
    const int NC = NKT / 2;
#pragma unroll
    for (int c = 0; c < NC; ++c) {
        __syncthreads();
#pragma unroll
        for (int s2 = 0; s2 < 2; ++s2) {
            *(v8bf*)&Bs[s2][bn][ks * 16] = vb[s2][0];
            *(v8bf*)&Bs[s2][bn][ks * 16 + 8] = vb[s2][1];
        }
        __syncthreads();
        if (c + 1 < NC) loadBreg(c + 1);
#pragma unroll
        for (int s = 0; s < 2; ++s) {
            int kt = c * 2 + s;
#pragma unroll
            for (int nt = 0; nt < 8; ++nt) {
                v8bf bh = *(v8bf*)&Bs[s][nt * 16 + lr][q * 8];
                acc[nt] = __builtin_amdgcn_mfma_f32_16x16x32_bf16(
                    afrag[kt], bh, acc[nt], 0, 0, 0);
            }
        }
    }

    if (epi == 2 && t < 128) { sS[t] = 0.f; sQ[t] = 0.f; }
    if (pathk || epi == 2) __syncthreads();

    float bcol[8];
#pragma unroll
    for (int nt = 0; nt < 8; ++nt) bcol[nt] = bias[n0 + nt * 16 + lr];

    if (epi == 0) {
#pragma unroll
        for (int reg = 0; reg < 4; ++reg) {
            int r2 = w * 16 + q * 4 + reg;
            int rm = m0 + r2;
            if (r2 < mtile && rm < M) {
#pragma unroll
                for (int nt = 0; nt < 8; ++nt) {
                    int cn = nt * 16 + lr;
                    float v = acc[nt][reg] + bcol[nt];
                    if (relu_flag) v = fmaxf(v, 0.f);
                    if (res) {
                        float rvl = (float)res[(size_t)rm * Ncol + n0 + cn];
                        if (bnmode == 2) rvl = fmaxf(rvl * scB[cn] + shB[cn], 0.f);
                        v += rvl;
                    }
                    out[(size_t)rm * Ncol + n0 + cn] = (__bf16)v;
                }
            }
        }
    } else {  // epi == 2: bf16 write + column stats
#pragma unroll
        for (int nt = 0; nt < 8; ++nt) {
            int cn = nt * 16 + lr;
            float s = 0.f, q2 = 0.f;
#pragma unroll
            for (int reg = 0; reg < 4; ++reg) {
                int r2 = w * 16 + q * 4 + reg;
                int rm = m0 + r2;
                if (r2 < mtile && rm < M) {
                    float v = acc[nt][reg] + bcol[nt];
                    out[(size_t)rm * Ncol + n0 + cn] = (__bf16)v;
                    s += v;
                    q2 += v * v;
                }
            }
            atomicAdd(&sS[cn], s);
            atomicAdd(&sQ[cn], q2);
        }
        __syncthreads();
        if (t < 128) {
            atomicAdd(&stats[n0 + t], sS[t]);
            atomicAdd(&stats[Ncol + n0 + t], sQ[t]);
        }
    }
}

// ---------------- MLP pass B: x = relu(BN1(h1')) @ gw2 + gb2, + BN2 stats ----------
// 64-row blocks; A16 K=256 preloaded upfront; BN1 fold + hi/lo split in-register.

__global__ __launch_bounds__(256) void k_mgemm_bn(
    const __bf16* __restrict__ A16, const __bf16* __restrict__ Bth,
    const float* __restrict__ gb2, const float* __restrict__ statsIn,
    const float* __restrict__ gbn_g, const float* __restrict__ gbn_b,
    __bf16* __restrict__ outx, float* __restrict__ stats2, int M)
{
    __shared__ __bf16 Bs[2][128][40];
    __shared__ float scS[256], shS[256];
    __shared__ float sS[128], sQ[128];

    int t = threadIdx.x;
    int m0 = blockIdx.x * 64;
    int lane = t & 63, q = lane >> 4, lr = lane & 15;
    int w = t >> 6;

    {
        float mean = statsIn[t] * (1.f / (float)Nn);
        float var = statsIn[256 + t] * (1.f / (float)Nn) - mean * mean;
        float s = gbn_g[t] * rsqrtf(var + BN_EPS);
        scS[t] = s;
        shS[t] = gbn_b[t] - mean * s;
    }
    if (t < 128) { sS[t] = 0.f; sQ[t] = 0.f; }

    int rloc = w * 16 + lr;
    int gm = m0 + rloc;
    bool rvalid = (gm < M);
    v8bf araw[8];
#pragma unroll
    for (int kt = 0; kt < 8; ++kt) {
        v8bf hv = {};
        if (rvalid) hv = *(const v8bf*)(A16 + (size_t)gm * 256 + kt * 32 + q * 8);
        araw[kt] = hv;
    }
    __syncthreads();  // scS/shS ready

    v8bf ah[8], al[8];
#pragma unroll
    for (int kt = 0; kt < 8; ++kt) {
        int kb = kt * 32 + q * 8;
#pragma unroll
        for (int i = 0; i < 8; ++i) {
            float tv = rvalid
                ? fmaxf((float)araw[kt][i] * scS[kb + i] + shS[kb + i], 0.f) : 0.f;
            bfpair p = split2(tv);
            ah[kt][i] = p.h;
            al[kt][i] = p.l;
        }
    }

    v4f acc[8] = {};
    int bn = t & 127;
    int ks = t >> 7;
    v8bf vb[2][2];
    auto loadBreg = [&](int c) {
#pragma unroll
        for (int s2 = 0; s2 < 2; ++s2) {
            const __bf16* bp = Bth + (size_t)bn * 256 + (c << 6) + s2 * 32 + ks * 16;
            vb[s2][0] = *(const v8bf*)bp;
            vb[s2][1] = *(const v8bf*)(bp + 8);
        }
    };
    loadBreg(0);
#pragma unroll
    for (int c = 0; c < 4; ++c) {
        __syncthreads();
#pragma unroll
        for (int s2 = 0; s2 < 2; ++s2) {
            *(v8bf*)&Bs[s2][bn][ks * 16] = vb[s2][0];
            *(v8bf*)&Bs[s2][bn][ks * 16 + 8] = vb[s2][1];
        }
        __syncthreads();
        if (c + 1 < 4) loadBreg(c + 1);
#pragma unroll
        for (int s = 0; s < 2; ++s) {
            int kt = c * 2 + s;
#pragma unroll
            for (int nt = 0; nt < 8; ++nt) {
                v8bf bh = *(v8bf*)&Bs[s][nt * 16 + lr][q * 8];
                acc[nt] = __builtin_amdgcn_mfma_f32_16x16x32_bf16(al[kt], bh, acc[nt], 0, 0, 0);
                acc[nt] = __builtin_amdgcn_mfma_f32_16x16x32_bf16(ah[kt], bh, acc[nt], 0, 0, 0);
            }
        }
    }

    __syncthreads();
    float bcol[8];
#pragma unroll
    for (int nt = 0; nt < 8; ++nt) bcol[nt] = gb2[nt * 16 + lr];
#pragma unroll
    for (int nt = 0; nt < 8; ++nt) {
        int cn = nt * 16 + lr;
        float s = 0.f, q2 = 0.f;
#pragma unroll
        for (int reg = 0; reg < 4; ++reg) {
            int rm = m0 + w * 16 + q * 4 + reg;
            if (rm < M) {
                float v = acc[nt][reg] + bcol[nt];
                outx[(size_t)rm * H + cn] = (__bf16)v;
                s += v;
                q2 += v * v;
            }
        }
        atomicAdd(&sS[cn], s);
        atomicAdd(&sQ[cn], q2);
    }
    __syncthreads();
    if (t < 128) {
        atomicAdd(&stats2[t], sS[t]);
        atomicAdd(&stats2[128 + t], sQ[t]);
    }
}

// ---------------- readout ----------------

__global__ void k_seg_batch(const __bf16* __restrict__ x, const int* __restrict__ batch,
                            float* __restrict__ xgsum, float* __restrict__ gcnt) {
    int h = threadIdx.x;
    int r0 = blockIdx.x * 256;
    if (r0 >= Nn) return;
    int r1 = min(r0 + 256, Nn);
    int cur = batch[r0];
    float acc = 0.f, c = 0.f;
    for (int r = r0; r < r1; ++r) {
        int b = batch[r];
        if (b != cur) {
            atomicAdd(&xgsum[cur * H + h], acc);
            if (h == 0) atomicAdd(&gcnt[cur], c);
            acc = 0.f;
            c = 0.f;
            cur = b;
        }
        acc += (float)x[(size_t)r * H + h];
        c += 1.f;
    }
    atomicAdd(&xgsum[cur * H + h], acc);
    if (h == 0) atomicAdd(&gcnt[cur], c);
}

__global__ void k_head(const float* __restrict__ xgsum, const float* __restrict__ gcnt,
                       const float* __restrict__ alw, const float* __restrict__ alb,
                       const float* __restrict__ lw, const float* __restrict__ lb,
                       float* __restrict__ out) {
    __shared__ float mean[H];
    __shared__ float red[H];
    int g = blockIdx.x, j = threadIdx.x;
    mean[j] = xgsum[g * H + j] / fmaxf(gcnt[g], 1.f);
    __syncthreads();
    float acc = alb[j];
    for (int k = 0; k < H; ++k) acc += mean[k] * alw[k * H + j];
    acc = fmaxf(acc, 0.f) * lw[j];
    red[j] = acc;
    __syncthreads();
    for (int s = 64; s > 0; s >>= 1) {
        if (j < s) red[j] += red[j + s];
        __syncthreads();
    }
    if (j == 0) out[g] = red[0] + lb[0];
}

// ---------------- host ----------------

extern "C" void kernel_launch(void* const* d_in, const int* in_sizes, int n_in,
                              void* d_out, int out_size, void* d_ws, size_t ws_size,
                              hipStream_t stream) {
    const int* x_atom = (const int*)d_in[0];
    const int* ei = (const int*)d_in[1];
    const int* eattr = (const int*)d_in[2];
    const int* batch = (const int*)d_in[3];
    const int* xc5 = (const int*)d_in[4];
    const int* xc6 = (const int*)d_in[5];
    const int* a2c5_row = (const int*)d_in[6];
    const int* a2c6_row = (const int*)d_in[8];
    const float* atom_emb = (const float*)d_in[10];
    const float* bond_emb = (const float*)d_in[11];
    const float* cyc5 = (const float*)d_in[12];
    const float* cyc6 = (const float*)d_in[13];
    const float* eps = (const float*)d_in[14];
    const float* gw1 = (const float*)d_in[15];
    const float* gb1 = (const float*)d_in[16];
    const float* gbn_g = (const float*)d_in[17];
    const float* gbn_b = (const float*)d_in[18];
    const float* gw2 = (const float*)d_in[19];
    const float* gb2 = (const float*)d_in[20];
    const float* bn_g = (const float*)d_in[21];
    const float* bn_b = (const float*)d_in[22];
    const float* a2c5_w = (const float*)d_in[23];
    const float* a2c5_b = (const float*)d_in[24];
    const float* a2c6_w = (const float*)d_in[25];
    const float* a2c6_b = (const float*)d_in[26];
    const float* c2a5_w = (const float*)d_in[27];
    const float* c2a5_b = (const float*)d_in[28];
    const float* c2a6_w = (const float*)d_in[29];
    const float* c2a6_b = (const float*)d_in[30];
    const float* p5_w = (const float*)d_in[31];
    const float* p5_b = (const float*)d_in[32];
    const float* p6_w = (const float*)d_in[33];
    const float* p6_b = (const float*)d_in[34];
    const float* alw = (const float*)d_in[35];
    const float* alb = (const float*)d_in[36];
    const float* lw = (const float*)d_in[37];
    const float* lb = (const float*)d_in[38];
    float* out = (float*)d_out;

    float* w = (float*)d_ws;
    size_t o = 0;
    auto alloc = [&](size_t nf) {
        float* p = w + o;
        o += (nf + 63) & ~(size_t)63;
        return p;
    };
    auto allocb = [&](size_t nbf) { return (__bf16*)alloc((nbf + 1) / 2); };
    __bf16* x = allocb((size_t)Nn * H);
    __bf16* x5 = allocb((size_t)N5c * 5 * H);
    __bf16* x6 = allocb((size_t)N6c * 6 * H);
    __bf16* agg = allocb((size_t)Nn * H);   // GINE agg / c2a gather buffer
    __bf16* h1b = allocb((size_t)Nn * 256);
    float* stats = alloc(512);
    float* stats2 = alloc(256);
    float* xgsum = alloc((size_t)Gg * H);
    float* gcnt = alloc(Gg);
    float* rscale5 = alloc(Nn);
    float* rscale6 = alloc(Nn);
    int* deg = (int*)alloc(Nn);
    int* rowptr = (int*)alloc(Nn + 1);
    int* rp5c = (int*)alloc(Nn + 1);
    int* rp6c = (int*)alloc(Nn + 1);
    int* woff = (int*)alloc(Nn);
    int* bsum = (int*)alloc(256);
    int* boff = (int*)alloc(256);
    unsigned int* elist = (unsigned int*)alloc(Ee);
    int* cidx5 = (int*)alloc(N5c * 5);
    int* cidx6 = (int*)alloc(N6c * 6);
    float* ebank = alloc(512 * H);
    __bf16* g1h = allocb(3 * 128 * 256);
    __bf16* g2h = allocb(3 * 256 * 128);
    __bf16* a5h = allocb(3 * 128 * 128);
    __bf16* a6h = allocb(3 * 128 * 128);
    __bf16* c5h = allocb(3 * 128 * 128);
    __bf16* c6h = allocb(3 * 128 * 128);
    __bf16* p5h = allocb(3 * 384 * 128);
    __bf16* p6h = allocb(3 * 384 * 128);

    const int TPB = 256;
    auto cdiv = [](int a, int b) { return (a + b - 1) / b; };
    int nsb = cdiv(Nn, 1024);

    // weight pre-split (transposed bf16 planes)
    k_split<<<cdiv(3 * 128 * 256, TPB), TPB, 0, stream>>>(gw1, g1h, 3, 128, 256);
    k_split<<<cdiv(3 * 256 * 128, TPB), TPB, 0, stream>>>(gw2, g2h, 3, 256, 128);
    k_split<<<cdiv(3 * 128 * 128, TPB), TPB, 0, stream>>>(a2c5_w, a5h, 3, 128, 128);
    k_split<<<cdiv(3 * 128 * 128, TPB), TPB, 0, stream>>>(a2c6_w, a6h, 3, 128, 128);
    k_split<<<cdiv(3 * 128 * 128, TPB), TPB, 0, stream>>>(c2a5_w, c5h, 3, 128, 128);
    k_split<<<cdiv(3 * 128 * 128, TPB), TPB, 0, stream>>>(c2a6_w, c6h, 3, 128, 128);
    k_split<<<cdiv(3 * 384 * 128, TPB), TPB, 0, stream>>>(p5_w, p5h, 3, 384, 128);
    k_split<<<cdiv(3 * 384 * 128, TPB), TPB, 0, stream>>>(p6_w, p6h, 3, 384, 128);

    // edge CSR
    hipMemsetAsync(deg, 0, Nn * 4, stream);
    k_degi<<<cdiv(Ee, TPB), TPB, 0, stream>>>(ei + Ee, deg, Ee);
    k_scan1<<<nsb, 256, 0, stream>>>(deg, rowptr, bsum, Nn);
    k_scan2<<<1, 128, 0, stream>>>(bsum, boff, rowptr, nsb, Nn);
    k_scan3<<<cdiv(Nn, TPB), TPB, 0, stream>>>(rowptr, boff, Nn);
    hipMemcpyAsync(woff, rowptr, Nn * 4, hipMemcpyDeviceToDevice, stream);
    k_fill<<<cdiv(Ee, TPB), TPB, 0, stream>>>(ei, eattr, woff, elist);

    // cycle->atom CSRs + mean scales
    hipMemsetAsync(deg, 0, Nn * 4, stream);
    k_degi<<<cdiv(N5c * 5, TPB), TPB, 0, stream>>>(a2c5_row, deg, N5c * 5);
    k_scan1<<<nsb, 256, 0, stream>>>(deg, rp5c, bsum, Nn);
    k_scan2<<<1, 128, 0, stream>>>(bsum, boff, rp5c, nsb, Nn);
    k_scan3<<<cdiv(Nn, TPB), TPB, 0, stream>>>(rp5c, boff, Nn);
    k_inv_int<<<cdiv(Nn, TPB), TPB, 0, stream>>>(deg, rscale5);
    hipMemcpyAsync(woff, rp5c, Nn * 4, hipMemcpyDeviceToDevice, stream);
    k_fill_idx<<<cdiv(N5c * 5, TPB), TPB, 0, stream>>>(a2c5_row, woff, cidx5, N5c * 5);

    hipMemsetAsync(deg, 0, Nn * 4, stream);
    k_degi<<<cdiv(N6c * 6, TPB), TPB, 0, stream>>>(a2c6_row, deg, N6c * 6);
    k_scan1<<<nsb, 256, 0, stream>>>(deg, rp6c, bsum, Nn);
    k_scan2<<<1, 128, 0, stream>>>(bsum, boff, rp6c, nsb, Nn);
    k_scan3<<<cdiv(Nn, TPB), TPB, 0, stream>>>(rp6c, boff, Nn);
    k_inv_int<<<cdiv(Nn, TPB), TPB, 0, stream>>>(deg, rscale6);
    hipMemcpyAsync(woff, rp6c, Nn * 4, hipMemcpyDeviceToDevice, stream);
    k_fill_idx<<<cdiv(N6c * 6, TPB), TPB, 0, stream>>>(a2c6_row, woff, cidx6, N6c * 6);

    k_atom_enc<<<cdiv(Nn * H, TPB), TPB, 0, stream>>>(x_atom, atom_emb, x);
    k_cyc_init<<<cdiv(N5c * 5 * H, TPB), TPB, 0, stream>>>(xc5, cyc5, x5, N5c * 5);
    k_cyc_init<<<cdiv(N6c * 6 * H, TPB), TPB, 0, stream>>>(xc6, cyc6, x6, N6c * 6);

    for (int i = 0; i < Ll; ++i) {
        // GINE aggregation (gather) -> agg
        k_ebank<<<cdiv(512 * H, TPB), TPB, 0, stream>>>(
            bond_emb + (size_t)i * BF * BV * H, ebank);
        k_agg_csr<<<Nn / 2, 256, 0, stream>>>(x, rowptr, elist, ebank, eps, i, agg);

        // MLP pass A: h1' = agg@gw1 + gb1 -> bf16 h1b, + BN1 stats
        hipMemsetAsync(stats, 0, 512 * 4, stream);
        k_mgemm<4><<<dim3(cdiv(Nn, 64), 2), 256, 0, stream>>>(
            agg, g1h + (size_t)i * 128 * 256, gb1 + (size_t)i * 256,
            nullptr, h1b, nullptr, stats, nullptr, nullptr, nullptr,
            Nn, 256, 0, 64, 0, 2, 0);

        // MLP pass B: x_raw = relu(BN1(h1')) @ gw2 + gb2 (pre-BN2), + BN2 stats
        hipMemsetAsync(stats2, 0, 256 * 4, stream);
        k_mgemm_bn<<<cdiv(Nn, 64), 256, 0, stream>>>(
            h1b, g2h + (size_t)i * 256 * 128, gb2 + (size_t)i * H,
            stats, gbn_g + (size_t)i * 256, gbn_b + (size_t)i * 256,
            x, stats2, Nn);

        // atoms -> cycles (row-gather GEMM with folded BN2+relu on A, in-place res)
        k_mgemm<4><<<cdiv(N5c * 5, 64), 256, 0, stream>>>(
            x, a5h + (size_t)i * 128 * 128, a2c5_b + (size_t)i * H,
            x5, x5, a2c5_row, nullptr,
            stats2, bn_g + (size_t)i * H, bn_b + (size_t)i * H,
            N5c * 5, 128, 0, 64, 1, 0, 1);
        k_mgemm<4><<<cdiv(N6c * 6, 64), 256, 0, stream>>>(
            x, a6h + (size_t)i * 128 * 128, a2c6_b + (size_t)i * H,
            x6, x6, a2c6_row, nullptr,
            stats2, bn_g + (size_t)i * H, bn_b + (size_t)i * H,
            N6c * 6, 128, 0, 64, 1, 0, 1);

        // cyclic path blocks: cycle-aligned 60-row tiles, fully in-place
        k_mgemm<12><<<cdiv(N5c * 5, 60), 256, 0, stream>>>(
            x5, p5h + (size_t)i * 384 * 128, p5_b + (size_t)i * H,
            x5, x5, nullptr, nullptr, nullptr, nullptr, nullptr,
            N5c * 5, 128, 5, 60, 1, 0, 0);
        k_mgemm<12><<<cdiv(N6c * 6, 60), 256, 0, stream>>>(
            x6, p6h + (size_t)i * 384 * 128, p6_b + (size_t)i * H,
            x6, x6, nullptr, nullptr, nullptr, nullptr, nullptr,
            N6c * 6, 128, 6, 60, 1, 0, 0);

        // cycles -> atoms: pre-gather mean into agg, then plain GEMM
        k_gmean<<<cdiv(Nn * 16, TPB), TPB, 0, stream>>>(x5, rp5c, cidx5, rscale5, agg);
        k_mgemm<4><<<cdiv(Nn, 64), 256, 0, stream>>>(
            agg, c5h + (size_t)i * 128 * 128, c2a5_b + (size_t)i * H,
            x, x, nullptr, nullptr,
            stats2, bn_g + (size_t)i * H, bn_b + (size_t)i * H,
            Nn, 128, 0, 64, 1, 0, 2);
        k_gmean<<<cdiv(Nn * 16, TPB), TPB, 0, stream>>>(x6, rp6c, cidx6, rscale6, agg);
        k_mgemm<4><<<cdiv(Nn, 64), 256, 0, stream>>>(
            agg, c6h + (size_t)i * 128 * 128, c2a6_b + (size_t)i * H,
            x, x, nullptr, nullptr, nullptr, nullptr, nullptr,
            Nn, 128, 0, 64, 1, 0, 0);
    }

    // readout
    hipMemsetAsync(xgsum, 0, (size_t)Gg * H * 4, stream);
    hipMemsetAsync(gcnt, 0, (size_t)Gg * 4, stream);
    k_seg_batch<<<cdiv(Nn, 256), H, 0, stream>>>(x, batch, xgsum, gcnt);
    k_head<<<Gg, H, 0, stream>>>(xgsum, gcnt, alw, alb, lw, lb, out);
}

// Round 14
// 1965.156 us; speedup vs baseline: 1.0756x; 1.0756x over previous
//
#include <hip/hip_runtime.h>

#define H 128
#define Nn 100000
#define Ee 250000
#define N5c 20000
#define N6c 30000
#define Gg 512
#define Ll 3
#define AF 9
#define AV 64
#define BF 3
#define BV 8
#define BN_EPS 1e-5f

typedef __bf16 v8bf __attribute__((ext_vector_type(8)));
typedef float v4f __attribute__((ext_vector_type(4)));

struct bfpair { __bf16 h, l; };
__device__ inline bfpair split2(float v) {
    bfpair r;
    r.h = (__bf16)v;
    r.l = (__bf16)(v - (float)r.h);
    return r;
}

// ---------------- init / embedding kernels ----------------

__global__ void k_atom_enc(const int* __restrict__ xa, const float* __restrict__ emb,
                           __bf16* __restrict__ x) {
    int idx = blockIdx.x * blockDim.x + threadIdx.x;
    if (idx >= Nn * H) return;
    int n = idx >> 7, h = idx & 127;
    float s = 0.f;
#pragma unroll
    for (int f = 0; f < AF; ++f) {
        int a = xa[n * AF + f];
        s += emb[(f * AV + a) * H + h];
    }
    x[idx] = (__bf16)s;
}

__global__ void k_cyc_init(const int* __restrict__ xc, const float* __restrict__ emb,
                           __bf16* __restrict__ xo, int M) {
    int idx = blockIdx.x * blockDim.x + threadIdx.x;
    if (idx >= M * H) return;
    int m = idx >> 7, h = idx & 127;
    xo[idx] = (__bf16)emb[xc[m] * H + h];
}

// weight pre-split: (L,K,N) fp32 row-major -> per-layer transposed [n][k] bf16
__global__ void k_split(const float* __restrict__ src, __bf16* __restrict__ dh,
                        int L, int K, int N) {
    int idx = blockIdx.x * blockDim.x + threadIdx.x;
    int tot = L * K * N;
    if (idx >= tot) return;
    int l = idx / (K * N);
    int r = idx - l * (K * N);
    int k = r / N;
    int n = r - k * N;
    size_t d = (size_t)l * K * N + (size_t)n * K + k;
    dh[d] = (__bf16)src[idx];
}

// ---------------- CSR build helpers ----------------

__global__ void k_degi(const int* __restrict__ row, int* __restrict__ deg, int M) {
    int m = blockIdx.x * blockDim.x + threadIdx.x;
    if (m >= M) return;
    atomicAdd(&deg[row[m]], 1);
}

__global__ void k_scan1(const int* __restrict__ deg, int* __restrict__ rp,
                        int* __restrict__ bsum, int n) {
    __shared__ int s[256];
    int tid = threadIdx.x;
    int base = blockIdx.x * 1024 + tid * 4;
    int v0 = (base < n) ? deg[base] : 0;
    int v1 = (base + 1 < n) ? deg[base + 1] : 0;
    int v2 = (base + 2 < n) ? deg[base + 2] : 0;
    int v3 = (base + 3 < n) ? deg[base + 3] : 0;
    int tsum = v0 + v1 + v2 + v3;
    s[tid] = tsum;
    __syncthreads();
    for (int off = 1; off < 256; off <<= 1) {
        int u = (tid >= off) ? s[tid - off] : 0;
        __syncthreads();
        s[tid] += u;
        __syncthreads();
    }
    int exc = s[tid] - tsum;
    if (base < n) rp[base] = exc;
    if (base + 1 < n) rp[base + 1] = exc + v0;
    if (base + 2 < n) rp[base + 2] = exc + v0 + v1;
    if (base + 3 < n) rp[base + 3] = exc + v0 + v1 + v2;
    if (tid == 255) bsum[blockIdx.x] = s[255];
}

__global__ void k_scan2(const int* __restrict__ bsum, int* __restrict__ boff,
                        int* __restrict__ rp, int nb, int n) {
    __shared__ int s[128];
    int tid = threadIdx.x;
    int v = (tid < nb) ? bsum[tid] : 0;
    s[tid] = v;
    __syncthreads();
    for (int off = 1; off < 128; off <<= 1) {
        int u = (tid >= off) ? s[tid - off] : 0;
        __syncthreads();
        s[tid] += u;
        __syncthreads();
    }
    if (tid < nb) boff[tid] = s[tid] - v;
    if (tid == 127) rp[n] = s[127];
}

__global__ void k_scan3(int* __restrict__ rp, const int* __restrict__ boff, int n) {
    int idx = blockIdx.x * blockDim.x + threadIdx.x;
    if (idx < n) rp[idx] += boff[idx >> 10];
}

__global__ void k_fill(const int* __restrict__ ei, const int* __restrict__ eattr,
                       int* __restrict__ woff, unsigned int* __restrict__ elist) {
    int e = blockIdx.x * blockDim.x + threadIdx.x;
    if (e >= Ee) return;
    int src = ei[e], dst = ei[Ee + e];
    int code = eattr[e * BF + 0] * 64 + eattr[e * BF + 1] * 8 + eattr[e * BF + 2];
    int p = atomicAdd(&woff[dst], 1);
    elist[p] = ((unsigned int)code << 17) | (unsigned int)src;
}

__global__ void k_fill_idx(const int* __restrict__ row, int* __restrict__ woff,
                           int* __restrict__ cidx, int M) {
    int m = blockIdx.x * blockDim.x + threadIdx.x;
    if (m >= M) return;
    int p = atomicAdd(&woff[row[m]], 1);
    cidx[p] = m;
}

__global__ void k_inv_int(const int* __restrict__ deg, float* __restrict__ rscale) {
    int r = blockIdx.x * blockDim.x + threadIdx.x;
    if (r >= Nn) return;
    rscale[r] = 1.f / fmaxf((float)deg[r], 1.f);
}

__global__ void k_ebank(const float* __restrict__ bemb, float* __restrict__ ebank) {
    int idx = blockIdx.x * blockDim.x + threadIdx.x;
    if (idx >= 512 * H) return;
    int code = idx >> 7, h = idx & 127;
    int f0 = code >> 6, f1 = (code >> 3) & 7, f2 = code & 7;
    ebank[idx] = bemb[(0 * BV + f0) * H + h] + bemb[(1 * BV + f1) * H + h]
               + bemb[(2 * BV + f2) * H + h];
}

// GINE aggregation, gather form
__global__ __launch_bounds__(256) void k_agg_csr(
    const __bf16* __restrict__ x, const int* __restrict__ rowptr,
    const unsigned int* __restrict__ elist, const float* __restrict__ ebank,
    const float* __restrict__ eps, int layer, __bf16* __restrict__ agg)
{
    int a = blockIdx.x * 2 + (threadIdx.x >> 7);
    int h = threadIdx.x & 127;
    float acc = (1.f + eps[layer]) * (float)x[(size_t)a * H + h];
    int j0 = rowptr[a], j1 = rowptr[a + 1];
    for (int j = j0; j < j1; ++j) {
        unsigned int u = elist[j];
        int src = u & 0x1FFFF;
        int code = u >> 17;
        acc += fmaxf((float)x[(size_t)src * H + h] + ebank[code * H + h], 0.f);
    }
    agg[(size_t)a * H + h] = (__bf16)acc;
}

// CSR mean-gather: out[a] = rscale[a] * sum_j xc[cidx[j]]  (bf16, vectorized)
__global__ __launch_bounds__(256) void k_gmean(
    const __bf16* __restrict__ xc, const int* __restrict__ grp,
    const int* __restrict__ gcol, const float* __restrict__ rscale,
    __bf16* __restrict__ outg)
{
    int idx = blockIdx.x * blockDim.x + threadIdx.x;
    if (idx >= Nn * 16) return;
    int a = idx >> 4, c8 = (idx & 15) * 8;
    int j0 = grp[a], j1 = grp[a + 1];
    float acc[8] = {0.f, 0.f, 0.f, 0.f, 0.f, 0.f, 0.f, 0.f};
    for (int j = j0; j < j1; ++j) {
        v8bf g = *(const v8bf*)(xc + (size_t)gcol[j] * H + c8);
#pragma unroll
        for (int i = 0; i < 8; ++i) acc[i] += (float)g[i];
    }
    float s = rscale[a];
    v8bf o;
#pragma unroll
    for (int i = 0; i < 8; ++i) o[i] = (__bf16)(acc[i] * s);
    *(v8bf*)(outg + (size_t)a * H + c8) = o;
}

// ---------------- MFMA GEMM: 64-row blocks, vectorized transpose epilogue ---------
// NKT = K/32. 4 waves x 16 rows; full-K A register preload; B chunked in LDS with
// register prefetch. Epilogue transposes C through LDS (aliasing B buffer) so
// res-reads and out-writes are 16-B vectorized.
// epi: 0 = bf16 out (+bf16 res/relu); 2 = bf16 out write + column stats.
// bnmode: 1 = folded BN+relu on A (K==128); 2 = folded BN+relu on res read.

template <int NKT>
__global__ __launch_bounds__(256) void k_mgemm(
    const __bf16* __restrict__ A, const __bf16* __restrict__ Bth,
    const float* __restrict__ bias, const __bf16* __restrict__ res,
    __bf16* __restrict__ out, const int* __restrict__ rowidx,
    float* __restrict__ stats,
    const float* __restrict__ bnstats, const float* __restrict__ bng,
    const float* __restrict__ bnb,
    int M, int Ncol, int pathk, int mtile, int relu_flag, int epi, int bnmode)
{
    const int K = NKT * 32;
    __shared__ __bf16 smem[2 * 128 * 40];  // B staging; reused as C transpose tile
    __shared__ float sS[128], sQ[128];
    __shared__ float scB[128], shB[128];
    auto Bs = reinterpret_cast<__bf16(*)[128][40]>(smem);

    int t = threadIdx.x;
    int m0 = blockIdx.x * mtile;
    int n0 = blockIdx.y * 128;
    int lane = t & 63, q = lane >> 4, lr = lane & 15;
    int w = t >> 6;

    if (bnmode && t < 128) {
        float mean = bnstats[t] * (1.f / (float)Nn);
        float var = bnstats[128 + t] * (1.f / (float)Nn) - mean * mean;
        float s = bng[t] * rsqrtf(var + BN_EPS);
        scB[t] = s;
        shB[t] = bnb[t] - mean * s;
    }

    // upfront A fragment preload (this wave's 16 rows; lane lr = row, q = k-quad)
    int rloc = w * 16 + lr;
    int gm = m0 + rloc;
    bool rvalid = (rloc < mtile) && (gm < M);
    v8bf afrag[NKT];
    {
        const __bf16* base = A;
        int cycb = 0, pm = 0;
        if (rvalid) {
            if (pathk) {
                int cyc = gm / pathk;
                cycb = cyc * pathk;
                pm = gm - cycb;
            } else if (rowidx) {
                base = A + (size_t)rowidx[gm] * H;
            } else {
                base = A + (size_t)gm * K;
            }
        }
#pragma unroll
        for (int kt = 0; kt < NKT; ++kt) {
            v8bf hv = {};
            if (rvalid) {
                if (pathk) {
                    int sel = kt >> 2;
                    int pp = pm + sel - 1;
                    if (pp < 0) pp += pathk;
                    if (pp >= pathk) pp -= pathk;
                    hv = *(const v8bf*)(A + (size_t)(cycb + pp) * H +
                                        ((kt * 32) & 127) + q * 8);
                } else {
                    hv = *(const v8bf*)(base + kt * 32 + q * 8);
                }
            }
            afrag[kt] = hv;
        }
    }
    if (bnmode == 1) {
        __syncthreads();  // scB ready
        if (rvalid) {
#pragma unroll
            for (int kt = 0; kt < NKT; ++kt) {
                int kb = kt * 32 + q * 8;
#pragma unroll
                for (int i = 0; i < 8; ++i)
                    afrag[kt][i] =
                        (__bf16)fmaxf((float)afrag[kt][i] * scB[kb + i] + shB[kb + i], 0.f);
            }
        }
    }

    v4f acc[8] = {};
    int bn = t & 127;
    int ks = t >> 7;

    v8bf vb[2][2];
    auto loadBreg = [&](int c) {
#pragma unroll
        for (int s2 = 0; s2 < 2; ++s2) {
            const __bf16* bp = Bth + (size_t)(n0 + bn) * K + (c << 6) + s2 * 32 + ks * 16;
            vb[s2][0] = *(const v8bf*)bp;
            vb[s2][1] = *(const v8bf*)(bp + 8);
        }
    };
    loadBreg(0);
    const int NC = NKT / 2;
#pragma unroll
    for (int c = 0; c < NC; ++c) {
        __syncthreads();
#pragma unroll
        for (int s2 = 0; s2 < 2; ++s2) {
            *(v8bf*)&Bs[s2][bn][ks * 16] = vb[s2][0];
            *(v8bf*)&Bs[s2][bn][ks * 16 + 8] = vb[s2][1];
        }
        __syncthreads();
        if (c + 1 < NC) loadBreg(c + 1);
#pragma unroll
        for (int s = 0; s < 2; ++s) {
            int kt = c * 2 + s;
#pragma unroll
            for (int nt = 0; nt < 8; ++nt) {
                v8bf bh = *(v8bf*)&Bs[s][nt * 16 + lr][q * 8];
                acc[nt] = __builtin_amdgcn_mfma_f32_16x16x32_bf16(
                    afrag[kt], bh, acc[nt], 0, 0, 0);
            }
        }
    }

    // ---- epilogue ----
    if (epi == 2 && t < 128) { sS[t] = 0.f; sQ[t] = 0.f; }
    __syncthreads();  // MFMA + B-LDS reads done; smem reusable; sS/sQ init visible

    float bcol[8];
#pragma unroll
    for (int nt = 0; nt < 8; ++nt) bcol[nt] = bias[n0 + nt * 16 + lr];

    if (epi == 2) {
#pragma unroll
        for (int nt = 0; nt < 8; ++nt) {
            float s = 0.f, q2 = 0.f;
#pragma unroll
            for (int reg = 0; reg < 4; ++reg) {
                int r2 = w * 16 + q * 4 + reg;
                int rm = m0 + r2;
                if (r2 < mtile && rm < M) {
                    float v = acc[nt][reg] + bcol[nt];
                    s += v;
                    q2 += v * v;
                }
            }
            atomicAdd(&sS[nt * 16 + lr], s);
            atomicAdd(&sQ[nt * 16 + lr], q2);
        }
    }
    // transpose accumulators into LDS (bf16)
    __bf16* Ct = smem;  // [64][136]
#pragma unroll
    for (int nt = 0; nt < 8; ++nt)
#pragma unroll
        for (int reg = 0; reg < 4; ++reg) {
            int row = w * 16 + q * 4 + reg;
            float v = acc[nt][reg] + bcol[nt];
            if (relu_flag) v = fmaxf(v, 0.f);
            Ct[row * 136 + nt * 16 + lr] = (__bf16)v;
        }
    __syncthreads();
    // vectorized global write (+res)
    {
        int row = t >> 2;
        int c0 = (t & 3) * 32;
        int rm = m0 + row;
        if (row < mtile && rm < M) {
#pragma unroll
            for (int seg = 0; seg < 4; ++seg) {
                int cc = c0 + seg * 8;
                v8bf cv = *(v8bf*)&Ct[row * 136 + cc];
                if (res) {
                    v8bf rv2 = *(const v8bf*)&res[(size_t)rm * Ncol + n0 + cc];
#pragma unroll
                    for (int i = 0; i < 8; ++i) {
                        float rf = (float)rv2[i];
                        if (bnmode == 2)
                            rf = fmaxf(rf * scB[cc + i] + shB[cc + i], 0.f);
                        cv[i] = (__bf16)((float)cv[i] + rf);
                    }
                }
                *(v8bf*)&out[(size_t)rm * Ncol + n0 + cc] = cv;
            }
        }
        if (epi == 2 && t < 128) {
            atomicAdd(&stats[n0 + t], sS[t]);
            atomicAdd(&stats[Ncol + n0 + t], sQ[t]);
        }
    }
}

// ---------------- MLP pass B: x = relu(BN1(h1')) @ gw2 + gb2, + BN2 stats ----------

__global__ __launch_bounds__(256) void k_mgemm_bn(
    const __bf16* __restrict__ A16, const __bf16* __restrict__ Bth,
    const float* __restrict__ gb2, const float* __restrict__ statsIn,
    const float* __restrict__ gbn_g, const float* __restrict__ gbn_b,
    __bf16* __restrict__ outx, float* __restrict__ stats2, int M)
{
    __shared__ __bf16 smem[2 * 128 * 40];
    __shared__ float scS[256], shS[256];
    __shared__ float sS[128], sQ[128];
    auto Bs = reinterpret_cast<__bf16(*)[128][40]>(smem);

    int t = threadIdx.x;
    int m0 = blockIdx.x * 64;
    int lane = t & 63, q = lane >> 4, lr = lane & 15;
    int w = t >> 6;

    {
        float mean = statsIn[t] * (1.f / (float)Nn);
        float var = statsIn[256 + t] * (1.f / (float)Nn) - mean * mean;
        float s = gbn_g[t] * rsqrtf(var + BN_EPS);
        scS[t] = s;
        shS[t] = gbn_b[t] - mean * s;
    }
    if (t < 128) { sS[t] = 0.f; sQ[t] = 0.f; }

    int rloc = w * 16 + lr;
    int gm = m0 + rloc;
    bool rvalid = (gm < M);
    v8bf araw[8];
#pragma unroll
    for (int kt = 0; kt < 8; ++kt) {
        v8bf hv = {};
        if (rvalid) hv = *(const v8bf*)(A16 + (size_t)gm * 256 + kt * 32 + q * 8);
        araw[kt] = hv;
    }
    __syncthreads();  // scS/shS ready

    v8bf ah[8], al[8];
#pragma unroll
    for (int kt = 0; kt < 8; ++kt) {
        int kb = kt * 32 + q * 8;
#pragma unroll
        for (int i = 0; i < 8; ++i) {
            float tv = rvalid
                ? fmaxf((float)araw[kt][i] * scS[kb + i] + shS[kb + i], 0.f) : 0.f;
            bfpair p = split2(tv);
            ah[kt][i] = p.h;
            al[kt][i] = p.l;
        }
    }

    v4f acc[8] = {};
    int bn = t & 127;
    int ks = t >> 7;
    v8bf vb[2][2];
    auto loadBreg = [&](int c) {
#pragma unroll
        for (int s2 = 0; s2 < 2; ++s2) {
            const __bf16* bp = Bth + (size_t)bn * 256 + (c << 6) + s2 * 32 + ks * 16;
            vb[s2][0] = *(const v8bf*)bp;
            vb[s2][1] = *(const v8bf*)(bp + 8);
        }
    };
    loadBreg(0);
#pragma unroll
    for (int c = 0; c < 4; ++c) {
        __syncthreads();
#pragma unroll
        for (int s2 = 0; s2 < 2; ++s2) {
            *(v8bf*)&Bs[s2][bn][ks * 16] = vb[s2][0];
            *(v8bf*)&Bs[s2][bn][ks * 16 + 8] = vb[s2][1];
        }
        __syncthreads();
        if (c + 1 < 4) loadBreg(c + 1);
#pragma unroll
        for (int s = 0; s < 2; ++s) {
            int kt = c * 2 + s;
#pragma unroll
            for (int nt = 0; nt < 8; ++nt) {
                v8bf bh = *(v8bf*)&Bs[s][nt * 16 + lr][q * 8];
                acc[nt] = __builtin_amdgcn_mfma_f32_16x16x32_bf16(al[kt], bh, acc[nt], 0, 0, 0);
                acc[nt] = __builtin_amdgcn_mfma_f32_16x16x32_bf16(ah[kt], bh, acc[nt], 0, 0, 0);
            }
        }
    }

    __syncthreads();  // B reads done; smem reusable
    float bcol[8];
#pragma unroll
    for (int nt = 0; nt < 8; ++nt) bcol[nt] = gb2[nt * 16 + lr];
    // stats from registers
#pragma unroll
    for (int nt = 0; nt < 8; ++nt) {
        float s = 0.f, q2 = 0.f;
#pragma unroll
        for (int reg = 0; reg < 4; ++reg) {
            int rm = m0 + w * 16 + q * 4 + reg;
            if (rm < M) {
                float v = acc[nt][reg] + bcol[nt];
                s += v;
                q2 += v * v;
            }
        }
        atomicAdd(&sS[nt * 16 + lr], s);
        atomicAdd(&sQ[nt * 16 + lr], q2);
    }
    // transpose into LDS, vectorized store
    __bf16* Ct = smem;
#pragma unroll
    for (int nt = 0; nt < 8; ++nt)
#pragma unroll
        for (int reg = 0; reg < 4; ++reg) {
            int row = w * 16 + q * 4 + reg;
            Ct[row * 136 + nt * 16 + lr] = (__bf16)(acc[nt][reg] + bcol[nt]);
        }
    __syncthreads();
    {
        int row = t >> 2;
        int c0 = (t & 3) * 32;
        int rm = m0 + row;
        if (rm < M) {
#pragma unroll
            for (int seg = 0; seg < 4; ++seg) {
                int cc = c0 + seg * 8;
                *(v8bf*)&outx[(size_t)rm * H + cc] = *(v8bf*)&Ct[row * 136 + cc];
            }
        }
        if (t < 128) {
            atomicAdd(&stats2[t], sS[t]);
            atomicAdd(&stats2[128 + t], sQ[t]);
        }
    }
}

// ---------------- readout ----------------

__global__ void k_seg_batch(const __bf16* __restrict__ x, const int* __restrict__ batch,
                            float* __restrict__ xgsum, float* __restrict__ gcnt) {
    int h = threadIdx.x;
    int r0 = blockIdx.x * 256;
    if (r0 >= Nn) return;
    int r1 = min(r0 + 256, Nn);
    int cur = batch[r0];
    float acc = 0.f, c = 0.f;
    for (int r = r0; r < r1; ++r) {
        int b = batch[r];
        if (b != cur) {
            atomicAdd(&xgsum[cur * H + h], acc);
            if (h == 0) atomicAdd(&gcnt[cur], c);
            acc = 0.f;
            c = 0.f;
            cur = b;
        }
        acc += (float)x[(size_t)r * H + h];
        c += 1.f;
    }
    atomicAdd(&xgsum[cur * H + h], acc);
    if (h == 0) atomicAdd(&gcnt[cur], c);
}

__global__ void k_head(const float* __restrict__ xgsum, const float* __restrict__ gcnt,
                       const float* __restrict__ alw, const float* __restrict__ alb,
                       const float* __restrict__ lw, const float* __restrict__ lb,
                       float* __restrict__ out) {
    __shared__ float mean[H];
    __shared__ float red[H];
    int g = blockIdx.x, j = threadIdx.x;
    mean[j] = xgsum[g * H + j] / fmaxf(gcnt[g], 1.f);
    __syncthreads();
    float acc = alb[j];
    for (int k = 0; k < H; ++k) acc += mean[k] * alw[k * H + j];
    acc = fmaxf(acc, 0.f) * lw[j];
    red[j] = acc;
    __syncthreads();
    for (int s = 64; s > 0; s >>= 1) {
        if (j < s) red[j] += red[j + s];
        __syncthreads();
    }
    if (j == 0) out[g] = red[0] + lb[0];
}

// ---------------- host ----------------

extern "C" void kernel_launch(void* const* d_in, const int* in_sizes, int n_in,
                              void* d_out, int out_size, void* d_ws, size_t ws_size,
                              hipStream_t stream) {
    const int* x_atom = (const int*)d_in[0];
    const int* ei = (const int*)d_in[1];
    const int* eattr = (const int*)d_in[2];
    const int* batch = (const int*)d_in[3];
    const int* xc5 = (const int*)d_in[4];
    const int* xc6 = (const int*)d_in[5];
    const int* a2c5_row = (const int*)d_in[6];
    const int* a2c6_row = (const int*)d_in[8];
    const float* atom_emb = (const float*)d_in[10];
    const float* bond_emb = (const float*)d_in[11];
    const float* cyc5 = (const float*)d_in[12];
    const float* cyc6 = (const float*)d_in[13];
    const float* eps = (const float*)d_in[14];
    const float* gw1 = (const float*)d_in[15];
    const float* gb1 = (const float*)d_in[16];
    const float* gbn_g = (const float*)d_in[17];
    const float* gbn_b = (const float*)d_in[18];
    const float* gw2 = (const float*)d_in[19];
    const float* gb2 = (const float*)d_in[20];
    const float* bn_g = (const float*)d_in[21];
    const float* bn_b = (const float*)d_in[22];
    const float* a2c5_w = (const float*)d_in[23];
    const float* a2c5_b = (const float*)d_in[24];
    const float* a2c6_w = (const float*)d_in[25];
    const float* a2c6_b = (const float*)d_in[26];
    const float* c2a5_w = (const float*)d_in[27];
    const float* c2a5_b = (const float*)d_in[28];
    const float* c2a6_w = (const float*)d_in[29];
    const float* c2a6_b = (const float*)d_in[30];
    const float* p5_w = (const float*)d_in[31];
    const float* p5_b = (const float*)d_in[32];
    const float* p6_w = (const float*)d_in[33];
    const float* p6_b = (const float*)d_in[34];
    const float* alw = (const float*)d_in[35];
    const float* alb = (const float*)d_in[36];
    const float* lw = (const float*)d_in[37];
    const float* lb = (const float*)d_in[38];
    float* out = (float*)d_out;

    float* w = (float*)d_ws;
    size_t o = 0;
    auto alloc = [&](size_t nf) {
        float* p = w + o;
        o += (nf + 63) & ~(size_t)63;
        return p;
    };
    auto allocb = [&](size_t nbf) { return (__bf16*)alloc((nbf + 1) / 2); };
    __bf16* x = allocb((size_t)Nn * H);
    __bf16* x5 = allocb((size_t)N5c * 5 * H);
    __bf16* x6 = allocb((size_t)N6c * 6 * H);
    __bf16* agg = allocb((size_t)Nn * H);
    __bf16* h1b = allocb((size_t)Nn * 256);
    float* stats = alloc(512);
    float* stats2 = alloc(256);
    float* xgsum = alloc((size_t)Gg * H);
    float* gcnt = alloc(Gg);
    float* rscale5 = alloc(Nn);
    float* rscale6 = alloc(Nn);
    int* deg = (int*)alloc(Nn);
    int* rowptr = (int*)alloc(Nn + 1);
    int* rp5c = (int*)alloc(Nn + 1);
    int* rp6c = (int*)alloc(Nn + 1);
    int* woff = (int*)alloc(Nn);
    int* bsum = (int*)alloc(256);
    int* boff = (int*)alloc(256);
    unsigned int* elist = (unsigned int*)alloc(Ee);
    int* cidx5 = (int*)alloc(N5c * 5);
    int* cidx6 = (int*)alloc(N6c * 6);
    float* ebank = alloc(512 * H);
    __bf16* g1h = allocb(3 * 128 * 256);
    __bf16* g2h = allocb(3 * 256 * 128);
    __bf16* a5h = allocb(3 * 128 * 128);
    __bf16* a6h = allocb(3 * 128 * 128);
    __bf16* c5h = allocb(3 * 128 * 128);
    __bf16* c6h = allocb(3 * 128 * 128);
    __bf16* p5h = allocb(3 * 384 * 128);
    __bf16* p6h = allocb(3 * 384 * 128);

    const int TPB = 256;
    auto cdiv = [](int a, int b) { return (a + b - 1) / b; };
    int nsb = cdiv(Nn, 1024);

    // weight pre-split (transposed bf16 planes)
    k_split<<<cdiv(3 * 128 * 256, TPB), TPB, 0, stream>>>(gw1, g1h, 3, 128, 256);
    k_split<<<cdiv(3 * 256 * 128, TPB), TPB, 0, stream>>>(gw2, g2h, 3, 256, 128);
    k_split<<<cdiv(3 * 128 * 128, TPB), TPB, 0, stream>>>(a2c5_w, a5h, 3, 128, 128);
    k_split<<<cdiv(3 * 128 * 128, TPB), TPB, 0, stream>>>(a2c6_w, a6h, 3, 128, 128);
    k_split<<<cdiv(3 * 128 * 128, TPB), TPB, 0, stream>>>(c2a5_w, c5h, 3, 128, 128);
    k_split<<<cdiv(3 * 128 * 128, TPB), TPB, 0, stream>>>(c2a6_w, c6h, 3, 128, 128);
    k_split<<<cdiv(3 * 384 * 128, TPB), TPB, 0, stream>>>(p5_w, p5h, 3, 384, 128);
    k_split<<<cdiv(3 * 384 * 128, TPB), TPB, 0, stream>>>(p6_w, p6h, 3, 384, 128);

    // edge CSR
    hipMemsetAsync(deg, 0, Nn * 4, stream);
    k_degi<<<cdiv(Ee, TPB), TPB, 0, stream>>>(ei + Ee, deg, Ee);
    k_scan1<<<nsb, 256, 0, stream>>>(deg, rowptr, bsum, Nn);
    k_scan2<<<1, 128, 0, stream>>>(bsum, boff, rowptr, nsb, Nn);
    k_scan3<<<cdiv(Nn, TPB), TPB, 0, stream>>>(rowptr, boff, Nn);
    hipMemcpyAsync(woff, rowptr, Nn * 4, hipMemcpyDeviceToDevice, stream);
    k_fill<<<cdiv(Ee, TPB), TPB, 0, stream>>>(ei, eattr, woff, elist);

    // cycle->atom CSRs + mean scales
    hipMemsetAsync(deg, 0, Nn * 4, stream);
    k_degi<<<cdiv(N5c * 5, TPB), TPB, 0, stream>>>(a2c5_row, deg, N5c * 5);
    k_scan1<<<nsb, 256, 0, stream>>>(deg, rp5c, bsum, Nn);
    k_scan2<<<1, 128, 0, stream>>>(bsum, boff, rp5c, nsb, Nn);
    k_scan3<<<cdiv(Nn, TPB), TPB, 0, stream>>>(rp5c, boff, Nn);
    k_inv_int<<<cdiv(Nn, TPB), TPB, 0, stream>>>(deg, rscale5);
    hipMemcpyAsync(woff, rp5c, Nn * 4, hipMemcpyDeviceToDevice, stream);
    k_fill_idx<<<cdiv(N5c * 5, TPB), TPB, 0, stream>>>(a2c5_row, woff, cidx5, N5c * 5);

    hipMemsetAsync(deg, 0, Nn * 4, stream);
    k_degi<<<cdiv(N6c * 6, TPB), TPB, 0, stream>>>(a2c6_row, deg, N6c * 6);
    k_scan1<<<nsb, 256, 0, stream>>>(deg, rp6c, bsum, Nn);
    k_scan2<<<1, 128, 0, stream>>>(bsum, boff, rp6c, nsb, Nn);
    k_scan3<<<cdiv(Nn, TPB), TPB, 0, stream>>>(rp6c, boff, Nn);
    k_inv_int<<<cdiv(Nn, TPB), TPB, 0, stream>>>(deg, rscale6);
    hipMemcpyAsync(woff, rp6c, Nn * 4, hipMemcpyDeviceToDevice, stream);
    k_fill_idx<<<cdiv(N6c * 6, TPB), TPB, 0, stream>>>(a2c6_row, woff, cidx6, N6c * 6);

    k_atom_enc<<<cdiv(Nn * H, TPB), TPB, 0, stream>>>(x_atom, atom_emb, x);
    k_cyc_init<<<cdiv(N5c * 5 * H, TPB), TPB, 0, stream>>>(xc5, cyc5, x5, N5c * 5);
    k_cyc_init<<<cdiv(N6c * 6 * H, TPB), TPB, 0, stream>>>(xc6, cyc6, x6, N6c * 6);

    for (int i = 0; i < Ll; ++i) {
        // GINE aggregation (gather) -> agg
        k_ebank<<<cdiv(512 * H, TPB), TPB, 0, stream>>>(
            bond_emb + (size_t)i * BF * BV * H, ebank);
        k_agg_csr<<<Nn / 2, 256, 0, stream>>>(x, rowptr, elist, ebank, eps, i, agg);

        // MLP pass A: h1' = agg@gw1 + gb1 -> bf16 h1b, + BN1 stats
        hipMemsetAsync(stats, 0, 512 * 4, stream);
        k_mgemm<4><<<dim3(cdiv(Nn, 64), 2), 256, 0, stream>>>(
            agg, g1h + (size_t)i * 128 * 256, gb1 + (size_t)i * 256,
            nullptr, h1b, nullptr, stats, nullptr, nullptr, nullptr,
            Nn, 256, 0, 64, 0, 2, 0);

        // MLP pass B: x_raw = relu(BN1(h1')) @ gw2 + gb2 (pre-BN2), + BN2 stats
        hipMemsetAsync(stats2, 0, 256 * 4, stream);
        k_mgemm_bn<<<cdiv(Nn, 64), 256, 0, stream>>>(
            h1b, g2h + (size_t)i * 256 * 128, gb2 + (size_t)i * H,
            stats, gbn_g + (size_t)i * 256, gbn_b + (size_t)i * 256,
            x, stats2, Nn);

        // atoms -> cycles (row-gather GEMM with folded BN2+relu on A, in-place res)
        k_mgemm<4><<<cdiv(N5c * 5, 64), 256, 0, stream>>>(
            x, a5h + (size_t)i * 128 * 128, a2c5_b + (size_t)i * H,
            x5, x5, a2c5_row,
            nullptr, stats2, bn_g + (size_t)i * H, bn_b + (size_t)i * H,
            N5c * 5, 128, 0, 64, 1, 0, 1);
        k_mgemm<4><<<cdiv(N6c * 6, 64), 256, 0, stream>>>(
            x, a6h + (size_t)i * 128 * 128, a2c6_b + (size_t)i * H,
            x6, x6, a2c6_row,
            nullptr, stats2, bn_g + (size_t)i * H, bn_b + (size_t)i * H,
            N6c * 6, 128, 0, 64, 1, 0, 1);

        // cyclic path blocks: cycle-aligned 60-row tiles, fully in-place
        k_mgemm<12><<<cdiv(N5c * 5, 60), 256, 0, stream>>>(
            x5, p5h + (size_t)i * 384 * 128, p5_b + (size_t)i * H,
            x5, x5, nullptr, nullptr, nullptr, nullptr, nullptr,
            N5c * 5, 128, 5, 60, 1, 0, 0);
        k_mgemm<12><<<cdiv(N6c * 6, 60), 256, 0, stream>>>(
            x6, p6h + (size_t)i * 384 * 128, p6_b + (size_t)i * H,
            x6, x6, nullptr, nullptr, nullptr, nullptr, nullptr,
            N6c * 6, 128, 6, 60, 1, 0, 0);

        // cycles -> atoms: pre-gather mean into agg, then plain GEMM
        k_gmean<<<cdiv(Nn * 16, TPB), TPB, 0, stream>>>(x5, rp5c, cidx5, rscale5, agg);
        k_mgemm<4><<<cdiv(Nn, 64), 256, 0, stream>>>(
            agg, c5h + (size_t)i * 128 * 128, c2a5_b + (size_t)i * H,
            x, x, nullptr,
            nullptr, stats2, bn_g + (size_t)i * H, bn_b + (size_t)i * H,
            Nn, 128, 0, 64, 1, 0, 2);
        k_gmean<<<cdiv(Nn * 16, TPB), TPB, 0, stream>>>(x6, rp6c, cidx6, rscale6, agg);
        k_mgemm<4><<<cdiv(Nn, 64), 256, 0, stream>>>(
            agg, c6h + (size_t)i * 128 * 128, c2a6_b + (size_t)i * H,
            x, x, nullptr, nullptr, nullptr, nullptr, nullptr,
            Nn, 128, 0, 64, 1, 0, 0);
    }

    // readout
    hipMemsetAsync(xgsum, 0, (size_t)Gg * H * 4, stream);
    hipMemsetAsync(gcnt, 0, (size_t)Gg * 4, stream);
    k_seg_batch<<<cdiv(Nn, 256), H, 0, stream>>>(x, batch, xgsum, gcnt);
    k_head<<<Gg, H, 0, stream>>>(xgsum, gcnt, alw, alb, lw, lb, out);
}

// Round 15
// 1964.347 us; speedup vs baseline: 1.0760x; 1.0004x over previous
//
#include <hip/hip_runtime.h>

#define H 128
#define Nn 100000
#define Ee 250000
#define N5c 20000
#define N6c 30000
#define Gg 512
#define Ll 3
#define AF 9
#define AV 64
#define BF 3
#define BV 8
#define BN_EPS 1e-5f

typedef __bf16 v8bf __attribute__((ext_vector_type(8)));
typedef float v4f __attribute__((ext_vector_type(4)));

struct bfpair { __bf16 h, l; };
__device__ inline bfpair split2(float v) {
    bfpair r;
    r.h = (__bf16)v;
    r.l = (__bf16)(v - (float)r.h);
    return r;
}

// ---------------- init / embedding kernels ----------------

__global__ void k_atom_enc(const int* __restrict__ xa, const float* __restrict__ emb,
                           __bf16* __restrict__ x) {
    int idx = blockIdx.x * blockDim.x + threadIdx.x;
    if (idx >= Nn * H) return;
    int n = idx >> 7, h = idx & 127;
    float s = 0.f;
#pragma unroll
    for (int f = 0; f < AF; ++f) {
        int a = xa[n * AF + f];
        s += emb[(f * AV + a) * H + h];
    }
    x[idx] = (__bf16)s;
}

__global__ void k_cyc_init(const int* __restrict__ xc, const float* __restrict__ emb,
                           __bf16* __restrict__ xo, int M) {
    int idx = blockIdx.x * blockDim.x + threadIdx.x;
    if (idx >= M * H) return;
    int m = idx >> 7, h = idx & 127;
    xo[idx] = (__bf16)emb[xc[m] * H + h];
}

// weight pre-split: (L,K,N) fp32 row-major -> per-layer transposed [n][k] bf16
__global__ void k_split(const float* __restrict__ src, __bf16* __restrict__ dh,
                        int L, int K, int N) {
    int idx = blockIdx.x * blockDim.x + threadIdx.x;
    int tot = L * K * N;
    if (idx >= tot) return;
    int l = idx / (K * N);
    int r = idx - l * (K * N);
    int k = r / N;
    int n = r - k * N;
    size_t d = (size_t)l * K * N + (size_t)n * K + k;
    dh[d] = (__bf16)src[idx];
}

// ---------------- CSR build helpers ----------------

__global__ void k_degi(const int* __restrict__ row, int* __restrict__ deg, int M) {
    int m = blockIdx.x * blockDim.x + threadIdx.x;
    if (m >= M) return;
    atomicAdd(&deg[row[m]], 1);
}

__global__ void k_scan1(const int* __restrict__ deg, int* __restrict__ rp,
                        int* __restrict__ bsum, int n) {
    __shared__ int s[256];
    int tid = threadIdx.x;
    int base = blockIdx.x * 1024 + tid * 4;
    int v0 = (base < n) ? deg[base] : 0;
    int v1 = (base + 1 < n) ? deg[base + 1] : 0;
    int v2 = (base + 2 < n) ? deg[base + 2] : 0;
    int v3 = (base + 3 < n) ? deg[base + 3] : 0;
    int tsum = v0 + v1 + v2 + v3;
    s[tid] = tsum;
    __syncthreads();
    for (int off = 1; off < 256; off <<= 1) {
        int u = (tid >= off) ? s[tid - off] : 0;
        __syncthreads();
        s[tid] += u;
        __syncthreads();
    }
    int exc = s[tid] - tsum;
    if (base < n) rp[base] = exc;
    if (base + 1 < n) rp[base + 1] = exc + v0;
    if (base + 2 < n) rp[base + 2] = exc + v0 + v1;
    if (base + 3 < n) rp[base + 3] = exc + v0 + v1 + v2;
    if (tid == 255) bsum[blockIdx.x] = s[255];
}

__global__ void k_scan2(const int* __restrict__ bsum, int* __restrict__ boff,
                        int* __restrict__ rp, int nb, int n) {
    __shared__ int s[128];
    int tid = threadIdx.x;
    int v = (tid < nb) ? bsum[tid] : 0;
    s[tid] = v;
    __syncthreads();
    for (int off = 1; off < 128; off <<= 1) {
        int u = (tid >= off) ? s[tid - off] : 0;
        __syncthreads();
        s[tid] += u;
        __syncthreads();
    }
    if (tid < nb) boff[tid] = s[tid] - v;
    if (tid == 127) rp[n] = s[127];
}

__global__ void k_scan3(int* __restrict__ rp, const int* __restrict__ boff, int n) {
    int idx = blockIdx.x * blockDim.x + threadIdx.x;
    if (idx < n) rp[idx] += boff[idx >> 10];
}

__global__ void k_fill(const int* __restrict__ ei, const int* __restrict__ eattr,
                       int* __restrict__ woff, unsigned int* __restrict__ elist) {
    int e = blockIdx.x * blockDim.x + threadIdx.x;
    if (e >= Ee) return;
    int src = ei[e], dst = ei[Ee + e];
    int code = eattr[e * BF + 0] * 64 + eattr[e * BF + 1] * 8 + eattr[e * BF + 2];
    int p = atomicAdd(&woff[dst], 1);
    elist[p] = ((unsigned int)code << 17) | (unsigned int)src;
}

__global__ void k_fill_idx(const int* __restrict__ row, int* __restrict__ woff,
                           int* __restrict__ cidx, int M) {
    int m = blockIdx.x * blockDim.x + threadIdx.x;
    if (m >= M) return;
    int p = atomicAdd(&woff[row[m]], 1);
    cidx[p] = m;
}

__global__ void k_inv_int(const int* __restrict__ deg, float* __restrict__ rscale) {
    int r = blockIdx.x * blockDim.x + threadIdx.x;
    if (r >= Nn) return;
    rscale[r] = 1.f / fmaxf((float)deg[r], 1.f);
}

__global__ void k_ebank(const float* __restrict__ bemb, float* __restrict__ ebank) {
    int idx = blockIdx.x * blockDim.x + threadIdx.x;
    if (idx >= 512 * H) return;
    int code = idx >> 7, h = idx & 127;
    int f0 = code >> 6, f1 = (code >> 3) & 7, f2 = code & 7;
    ebank[idx] = bemb[(0 * BV + f0) * H + h] + bemb[(1 * BV + f1) * H + h]
               + bemb[(2 * BV + f2) * H + h];
}

// GINE aggregation, gather form
__global__ __launch_bounds__(256) void k_agg_csr(
    const __bf16* __restrict__ x, const int* __restrict__ rowptr,
    const unsigned int* __restrict__ elist, const float* __restrict__ ebank,
    const float* __restrict__ eps, int layer, __bf16* __restrict__ agg)
{
    int a = blockIdx.x * 2 + (threadIdx.x >> 7);
    int h = threadIdx.x & 127;
    float acc = (1.f + eps[layer]) * (float)x[(size_t)a * H + h];
    int j0 = rowptr[a], j1 = rowptr[a + 1];
    for (int j = j0; j < j1; ++j) {
        unsigned int u = elist[j];
        int src = u & 0x1FFFF;
        int code = u >> 17;
        acc += fmaxf((float)x[(size_t)src * H + h] + ebank[code * H + h], 0.f);
    }
    agg[(size_t)a * H + h] = (__bf16)acc;
}

// CSR mean-gather: out[a] = rscale[a] * sum_j xc[cidx[j]]  (bf16, vectorized)
__global__ __launch_bounds__(256) void k_gmean(
    const __bf16* __restrict__ xc, const int* __restrict__ grp,
    const int* __restrict__ gcol, const float* __restrict__ rscale,
    __bf16* __restrict__ outg)
{
    int idx = blockIdx.x * blockDim.x + threadIdx.x;
    if (idx >= Nn * 16) return;
    int a = idx >> 4, c8 = (idx & 15) * 8;
    int j0 = grp[a], j1 = grp[a + 1];
    float acc[8] = {0.f, 0.f, 0.f, 0.f, 0.f, 0.f, 0.f, 0.f};
    for (int j = j0; j < j1; ++j) {
        v8bf g = *(const v8bf*)(xc + (size_t)gcol[j] * H + c8);
#pragma unroll
        for (int i = 0; i < 8; ++i) acc[i] += (float)g[i];
    }
    float s = rscale[a];
    v8bf o;
#pragma unroll
    for (int i = 0; i < 8; ++i) o[i] = (__bf16)(acc[i] * s);
    *(v8bf*)(outg + (size_t)a * H + c8) = o;
}

// ---------------- MFMA GEMM: 64-row blocks, vectorized transpose epilogue ---------

template <int NKT>
__global__ __launch_bounds__(256) void k_mgemm(
    const __bf16* __restrict__ A, const __bf16* __restrict__ Bth,
    const float* __restrict__ bias, const __bf16* __restrict__ res,
    __bf16* __restrict__ out, const int* __restrict__ rowidx,
    const float* __restrict__ bnstats, const float* __restrict__ bng,
    const float* __restrict__ bnb,
    int M, int Ncol, int pathk, int mtile, int relu_flag, int bnmode)
{
    const int K = NKT * 32;
    __shared__ __bf16 smem[2 * 128 * 40];  // B staging; reused as C transpose tile
    __shared__ float scB[128], shB[128];
    auto Bs = reinterpret_cast<__bf16(*)[128][40]>(smem);

    int t = threadIdx.x;
    int m0 = blockIdx.x * mtile;
    int n0 = blockIdx.y * 128;
    int lane = t & 63, q = lane >> 4, lr = lane & 15;
    int w = t >> 6;

    if (bnmode && t < 128) {
        float mean = bnstats[t] * (1.f / (float)Nn);
        float var = bnstats[128 + t] * (1.f / (float)Nn) - mean * mean;
        float s = bng[t] * rsqrtf(var + BN_EPS);
        scB[t] = s;
        shB[t] = bnb[t] - mean * s;
    }

    int rloc = w * 16 + lr;
    int gm = m0 + rloc;
    bool rvalid = (rloc < mtile) && (gm < M);
    v8bf afrag[NKT];
    {
        const __bf16* base = A;
        int cycb = 0, pm = 0;
        if (rvalid) {
            if (pathk) {
                int cyc = gm / pathk;
                cycb = cyc * pathk;
                pm = gm - cycb;
            } else if (rowidx) {
                base = A + (size_t)rowidx[gm] * H;
            } else {
                base = A + (size_t)gm * K;
            }
        }
#pragma unroll
        for (int kt = 0; kt < NKT; ++kt) {
            v8bf hv = {};
            if (rvalid) {
                if (pathk) {
                    int sel = kt >> 2;
                    int pp = pm + sel - 1;
                    if (pp < 0) pp += pathk;
                    if (pp >= pathk) pp -= pathk;
                    hv = *(const v8bf*)(A + (size_t)(cycb + pp) * H +
                                        ((kt * 32) & 127) + q * 8);
                } else {
                    hv = *(const v8bf*)(base + kt * 32 + q * 8);
                }
            }
            afrag[kt] = hv;
        }
    }
    if (bnmode == 1) {
        __syncthreads();
        if (rvalid) {
#pragma unroll
            for (int kt = 0; kt < NKT; ++kt) {
                int kb = kt * 32 + q * 8;
#pragma unroll
                for (int i = 0; i < 8; ++i)
                    afrag[kt][i] =
                        (__bf16)fmaxf((float)afrag[kt][i] * scB[kb + i] + shB[kb + i], 0.f);
            }
        }
    }

    v4f acc[8] = {};
    int bn = t & 127;
    int ks = t >> 7;

    v8bf vb[2][2];
    auto loadBreg = [&](int c) {
#pragma unroll
        for (int s2 = 0; s2 < 2; ++s2) {
            const __bf16* bp = Bth + (size_t)(n0 + bn) * K + (c << 6) + s2 * 32 + ks * 16;
            vb[s2][0] = *(const v8bf*)bp;
            vb[s2][1] = *(const v8bf*)(bp + 8);
        }
    };
    loadBreg(0);
    const int NC = NKT / 2;
#pragma unroll
    for (int c = 0; c < NC; ++c) {
        __syncthreads();
#pragma unroll
        for (int s2 = 0; s2 < 2; ++s2) {
            *(v8bf*)&Bs[s2][bn][ks * 16] = vb[s2][0];
            *(v8bf*)&Bs[s2][bn][ks * 16 + 8] = vb[s2][1];
        }
        __syncthreads();
        if (c + 1 < NC) loadBreg(c + 1);
#pragma unroll
        for (int s = 0; s < 2; ++s) {
            int kt = c * 2 + s;
#pragma unroll
            for (int nt = 0; nt < 8; ++nt) {
                v8bf bh = *(v8bf*)&Bs[s][nt * 16 + lr][q * 8];
                acc[nt] = __builtin_amdgcn_mfma_f32_16x16x32_bf16(
                    afrag[kt], bh, acc[nt], 0, 0, 0);
            }
        }
    }

    __syncthreads();  // MFMA + B-LDS reads done; smem reusable

    float bcol[8];
#pragma unroll
    for (int nt = 0; nt < 8; ++nt) bcol[nt] = bias[n0 + nt * 16 + lr];

    __bf16* Ct = smem;  // [64][136]
#pragma unroll
    for (int nt = 0; nt < 8; ++nt)
#pragma unroll
        for (int reg = 0; reg < 4; ++reg) {
            int row = w * 16 + q * 4 + reg;
            float v = acc[nt][reg] + bcol[nt];
            if (relu_flag) v = fmaxf(v, 0.f);
            Ct[row * 136 + nt * 16 + lr] = (__bf16)v;
        }
    __syncthreads();
    {
        int row = t >> 2;
        int c0 = (t & 3) * 32;
        int rm = m0 + row;
        if (row < mtile && rm < M) {
#pragma unroll
            for (int seg = 0; seg < 4; ++seg) {
                int cc = c0 + seg * 8;
                v8bf cv = *(v8bf*)&Ct[row * 136 + cc];
                if (res) {
                    v8bf rv2 = *(const v8bf*)&res[(size_t)rm * Ncol + n0 + cc];
#pragma unroll
                    for (int i = 0; i < 8; ++i) {
                        float rf = (float)rv2[i];
                        if (bnmode == 2)
                            rf = fmaxf(rf * scB[cc + i] + shB[cc + i], 0.f);
                        cv[i] = (__bf16)((float)cv[i] + rf);
                    }
                }
                *(v8bf*)&out[(size_t)rm * Ncol + n0 + cc] = cv;
            }
        }
    }
}

// ---------------- MLP pass A: BN1 column stats only (no h1 write) ----------------

__global__ __launch_bounds__(256) void k_mlp_statsA(
    const __bf16* __restrict__ agg, const __bf16* __restrict__ g1h,
    const float* __restrict__ gb1, float* __restrict__ stats, int M)
{
    __shared__ __bf16 smem[2 * 128 * 40];
    __shared__ float sS[256], sQ[256];
    auto Bs = reinterpret_cast<__bf16(*)[128][40]>(smem);

    int t = threadIdx.x;
    int m0 = blockIdx.x * 64;
    int lane = t & 63, q = lane >> 4, lr = lane & 15;
    int w = t >> 6;
    sS[t] = 0.f;
    sQ[t] = 0.f;

    int gm = m0 + w * 16 + lr;
    bool rvalid = (gm < M);
    v8bf afrag[4];
#pragma unroll
    for (int kt = 0; kt < 4; ++kt) {
        v8bf hv = {};
        if (rvalid) hv = *(const v8bf*)(agg + (size_t)gm * H + kt * 32 + q * 8);
        afrag[kt] = hv;
    }

    int bn = t & 127;
    int ks = t >> 7;
    v8bf vb[2][2];
    auto loadB = [&](int step) {  // step 0..3: panel p=step>>1, chunk c=step&1
        int p = step >> 1, c = step & 1;
        const __bf16* bp = g1h + (size_t)(p * 128 + bn) * 128 + (c << 6) + ks * 16;
#pragma unroll
        for (int s2 = 0; s2 < 2; ++s2) {
            vb[s2][0] = *(const v8bf*)(bp + s2 * 32);
            vb[s2][1] = *(const v8bf*)(bp + s2 * 32 + 8);
        }
    };
    loadB(0);
    for (int p = 0; p < 2; ++p) {
        v4f acc[8] = {};
#pragma unroll
        for (int c = 0; c < 2; ++c) {
            __syncthreads();
#pragma unroll
            for (int s2 = 0; s2 < 2; ++s2) {
                *(v8bf*)&Bs[s2][bn][ks * 16] = vb[s2][0];
                *(v8bf*)&Bs[s2][bn][ks * 16 + 8] = vb[s2][1];
            }
            __syncthreads();
            int step = p * 2 + c;
            if (step < 3) loadB(step + 1);
#pragma unroll
            for (int s = 0; s < 2; ++s) {
                int kt = c * 2 + s;
#pragma unroll
                for (int nt = 0; nt < 8; ++nt) {
                    v8bf bh = *(v8bf*)&Bs[s][nt * 16 + lr][q * 8];
                    acc[nt] = __builtin_amdgcn_mfma_f32_16x16x32_bf16(
                        afrag[kt], bh, acc[nt], 0, 0, 0);
                }
            }
        }
#pragma unroll
        for (int nt = 0; nt < 8; ++nt) {
            int col = p * 128 + nt * 16 + lr;
            float bv = gb1[col];
            float s = 0.f, q2 = 0.f;
#pragma unroll
            for (int reg = 0; reg < 4; ++reg) {
                int rm = m0 + w * 16 + q * 4 + reg;
                if (rm < M) {
                    float v = acc[nt][reg] + bv;
                    s += v;
                    q2 += v * v;
                }
            }
            atomicAdd(&sS[col], s);
            atomicAdd(&sQ[col], q2);
        }
    }
    __syncthreads();
    atomicAdd(&stats[t], sS[t]);
    atomicAdd(&stats[256 + t], sQ[t]);
}

// ---------------- MLP fused pass B: x = relu(BN1(agg@gw1+gb1)) @ gw2 + gb2 --------
// Recomputes GEMM1 in-register, folds BN1 (fp32) + relu, T to LDS, GEMM2, writes
// bf16 x_raw (pre-BN2) + BN2 stats. 64-row blocks.

__global__ __launch_bounds__(256) void k_mlp_fused(
    const __bf16* __restrict__ agg, const __bf16* __restrict__ g1h,
    const float* __restrict__ gb1, const float* __restrict__ statsIn,
    const float* __restrict__ gbn_g, const float* __restrict__ gbn_b,
    const __bf16* __restrict__ g2h, const float* __restrict__ gb2,
    __bf16* __restrict__ outx, float* __restrict__ stats2, int M)
{
    __shared__ __bf16 smem[2 * 128 * 40];   // B staging / C transpose
    __shared__ __bf16 Tt[64 * 264];         // T tile (bf16)
    __shared__ float scS[256], shS[256];
    __shared__ float sS[128], sQ[128];
    auto Bs = reinterpret_cast<__bf16(*)[128][40]>(smem);

    int t = threadIdx.x;
    int m0 = blockIdx.x * 64;
    int lane = t & 63, q = lane >> 4, lr = lane & 15;
    int w = t >> 6;

    {
        float mean = statsIn[t] * (1.f / (float)Nn);
        float var = statsIn[256 + t] * (1.f / (float)Nn) - mean * mean;
        float s = gbn_g[t] * rsqrtf(var + BN_EPS);
        scS[t] = s;
        shS[t] = (gb1[t] - mean) * s + gbn_b[t];  // fold gb1 too
    }
    if (t < 128) { sS[t] = 0.f; sQ[t] = 0.f; }

    int gm = m0 + w * 16 + lr;
    bool rvalid = (gm < M);
    v8bf afrag[4];
#pragma unroll
    for (int kt = 0; kt < 4; ++kt) {
        v8bf hv = {};
        if (rvalid) hv = *(const v8bf*)(agg + (size_t)gm * H + kt * 32 + q * 8);
        afrag[kt] = hv;
    }

    int bn = t & 127;
    int ks = t >> 7;
    v8bf vb[2][2];
    auto loadBany = [&](int step) {  // 0..3: g1h (panel,chunk); 4..7: g2h chunk
        const __bf16* bp;
        if (step < 4) {
            int p = step >> 1, c = step & 1;
            bp = g1h + (size_t)(p * 128 + bn) * 128 + (c << 6) + ks * 16;
        } else {
            int c = step - 4;
            bp = g2h + (size_t)bn * 256 + (c << 6) + ks * 16;
        }
#pragma unroll
        for (int s2 = 0; s2 < 2; ++s2) {
            vb[s2][0] = *(const v8bf*)(bp + s2 * 32);
            vb[s2][1] = *(const v8bf*)(bp + s2 * 32 + 8);
        }
    };
    loadBany(0);

    // stage 1
    for (int p = 0; p < 2; ++p) {
        v4f acc1[8] = {};
#pragma unroll
        for (int c = 0; c < 2; ++c) {
            __syncthreads();
#pragma unroll
            for (int s2 = 0; s2 < 2; ++s2) {
                *(v8bf*)&Bs[s2][bn][ks * 16] = vb[s2][0];
                *(v8bf*)&Bs[s2][bn][ks * 16 + 8] = vb[s2][1];
            }
            __syncthreads();
            loadBany(p * 2 + c + 1);  // steps 1..4 (4 = g2h chunk 0)
#pragma unroll
            for (int s = 0; s < 2; ++s) {
                int kt = c * 2 + s;
#pragma unroll
                for (int nt = 0; nt < 8; ++nt) {
                    v8bf bh = *(v8bf*)&Bs[s][nt * 16 + lr][q * 8];
                    acc1[nt] = __builtin_amdgcn_mfma_f32_16x16x32_bf16(
                        afrag[kt], bh, acc1[nt], 0, 0, 0);
                }
            }
        }
#pragma unroll
        for (int nt = 0; nt < 8; ++nt)
#pragma unroll
            for (int reg = 0; reg < 4; ++reg) {
                int row = w * 16 + q * 4 + reg;
                int col = p * 128 + nt * 16 + lr;
                float v = fmaxf(acc1[nt][reg] * scS[col] + shS[col], 0.f);
                Tt[row * 264 + col] = (__bf16)v;
            }
    }

    // stage 2: A from Tt (own wave's rows)
    __syncthreads();
    v8bf a2[8];
#pragma unroll
    for (int kt = 0; kt < 8; ++kt)
        a2[kt] = *(v8bf*)&Tt[(w * 16 + lr) * 264 + kt * 32 + q * 8];

    v4f acc2[8] = {};
#pragma unroll
    for (int c = 0; c < 4; ++c) {
        __syncthreads();
#pragma unroll
        for (int s2 = 0; s2 < 2; ++s2) {
            *(v8bf*)&Bs[s2][bn][ks * 16] = vb[s2][0];
            *(v8bf*)&Bs[s2][bn][ks * 16 + 8] = vb[s2][1];
        }
        __syncthreads();
        if (c < 3) loadBany(5 + c);
#pragma unroll
        for (int s = 0; s < 2; ++s) {
            int kt = c * 2 + s;
#pragma unroll
            for (int nt = 0; nt < 8; ++nt) {
                v8bf bh = *(v8bf*)&Bs[s][nt * 16 + lr][q * 8];
                acc2[nt] = __builtin_amdgcn_mfma_f32_16x16x32_bf16(
                    a2[kt], bh, acc2[nt], 0, 0, 0);
            }
        }
    }

    __syncthreads();
    float bcol[8];
#pragma unroll
    for (int nt = 0; nt < 8; ++nt) bcol[nt] = gb2[nt * 16 + lr];
#pragma unroll
    for (int nt = 0; nt < 8; ++nt) {
        float s = 0.f, q2 = 0.f;
#pragma unroll
        for (int reg = 0; reg < 4; ++reg) {
            int rm = m0 + w * 16 + q * 4 + reg;
            if (rm < M) {
                float v = acc2[nt][reg] + bcol[nt];
                s += v;
                q2 += v * v;
            }
        }
        atomicAdd(&sS[nt * 16 + lr], s);
        atomicAdd(&sQ[nt * 16 + lr], q2);
    }
    __bf16* Ct = smem;
#pragma unroll
    for (int nt = 0; nt < 8; ++nt)
#pragma unroll
        for (int reg = 0; reg < 4; ++reg) {
            int row = w * 16 + q * 4 + reg;
            Ct[row * 136 + nt * 16 + lr] = (__bf16)(acc2[nt][reg] + bcol[nt]);
        }
    __syncthreads();
    {
        int row = t >> 2;
        int c0 = (t & 3) * 32;
        int rm = m0 + row;
        if (rm < M) {
#pragma unroll
            for (int seg = 0; seg < 4; ++seg) {
                int cc = c0 + seg * 8;
                *(v8bf*)&outx[(size_t)rm * H + cc] = *(v8bf*)&Ct[row * 136 + cc];
            }
        }
        if (t < 128) {
            atomicAdd(&stats2[t], sS[t]);
            atomicAdd(&stats2[128 + t], sQ[t]);
        }
    }
}

// ---------------- readout ----------------

__global__ void k_seg_batch(const __bf16* __restrict__ x, const int* __restrict__ batch,
                            float* __restrict__ xgsum, float* __restrict__ gcnt) {
    int h = threadIdx.x;
    int r0 = blockIdx.x * 256;
    if (r0 >= Nn) return;
    int r1 = min(r0 + 256, Nn);
    int cur = batch[r0];
    float acc = 0.f, c = 0.f;
    for (int r = r0; r < r1; ++r) {
        int b = batch[r];
        if (b != cur) {
            atomicAdd(&xgsum[cur * H + h], acc);
            if (h == 0) atomicAdd(&gcnt[cur], c);
            acc = 0.f;
            c = 0.f;
            cur = b;
        }
        acc += (float)x[(size_t)r * H + h];
        c += 1.f;
    }
    atomicAdd(&xgsum[cur * H + h], acc);
    if (h == 0) atomicAdd(&gcnt[cur], c);
}

__global__ void k_head(const float* __restrict__ xgsum, const float* __restrict__ gcnt,
                       const float* __restrict__ alw, const float* __restrict__ alb,
                       const float* __restrict__ lw, const float* __restrict__ lb,
                       float* __restrict__ out) {
    __shared__ float mean[H];
    __shared__ float red[H];
    int g = blockIdx.x, j = threadIdx.x;
    mean[j] = xgsum[g * H + j] / fmaxf(gcnt[g], 1.f);
    __syncthreads();
    float acc = alb[j];
    for (int k = 0; k < H; ++k) acc += mean[k] * alw[k * H + j];
    acc = fmaxf(acc, 0.f) * lw[j];
    red[j] = acc;
    __syncthreads();
    for (int s = 64; s > 0; s >>= 1) {
        if (j < s) red[j] += red[j + s];
        __syncthreads();
    }
    if (j == 0) out[g] = red[0] + lb[0];
}

// ---------------- host ----------------

extern "C" void kernel_launch(void* const* d_in, const int* in_sizes, int n_in,
                              void* d_out, int out_size, void* d_ws, size_t ws_size,
                              hipStream_t stream) {
    const int* x_atom = (const int*)d_in[0];
    const int* ei = (const int*)d_in[1];
    const int* eattr = (const int*)d_in[2];
    const int* batch = (const int*)d_in[3];
    const int* xc5 = (const int*)d_in[4];
    const int* xc6 = (const int*)d_in[5];
    const int* a2c5_row = (const int*)d_in[6];
    const int* a2c6_row = (const int*)d_in[8];
    const float* atom_emb = (const float*)d_in[10];
    const float* bond_emb = (const float*)d_in[11];
    const float* cyc5 = (const float*)d_in[12];
    const float* cyc6 = (const float*)d_in[13];
    const float* eps = (const float*)d_in[14];
    const float* gw1 = (const float*)d_in[15];
    const float* gb1 = (const float*)d_in[16];
    const float* gbn_g = (const float*)d_in[17];
    const float* gbn_b = (const float*)d_in[18];
    const float* gw2 = (const float*)d_in[19];
    const float* gb2 = (const float*)d_in[20];
    const float* bn_g = (const float*)d_in[21];
    const float* bn_b = (const float*)d_in[22];
    const float* a2c5_w = (const float*)d_in[23];
    const float* a2c5_b = (const float*)d_in[24];
    const float* a2c6_w = (const float*)d_in[25];
    const float* a2c6_b = (const float*)d_in[26];
    const float* c2a5_w = (const float*)d_in[27];
    const float* c2a5_b = (const float*)d_in[28];
    const float* c2a6_w = (const float*)d_in[29];
    const float* c2a6_b = (const float*)d_in[30];
    const float* p5_w = (const float*)d_in[31];
    const float* p5_b = (const float*)d_in[32];
    const float* p6_w = (const float*)d_in[33];
    const float* p6_b = (const float*)d_in[34];
    const float* alw = (const float*)d_in[35];
    const float* alb = (const float*)d_in[36];
    const float* lw = (const float*)d_in[37];
    const float* lb = (const float*)d_in[38];
    float* out = (float*)d_out;

    float* w = (float*)d_ws;
    size_t o = 0;
    auto alloc = [&](size_t nf) {
        float* p = w + o;
        o += (nf + 63) & ~(size_t)63;
        return p;
    };
    auto allocb = [&](size_t nbf) { return (__bf16*)alloc((nbf + 1) / 2); };
    __bf16* x = allocb((size_t)Nn * H);
    __bf16* x5 = allocb((size_t)N5c * 5 * H);
    __bf16* x6 = allocb((size_t)N6c * 6 * H);
    __bf16* agg = allocb((size_t)Nn * H);
    float* stats = alloc(512);
    float* stats2 = alloc(256);
    float* xgsum = alloc((size_t)Gg * H);
    float* gcnt = alloc(Gg);
    float* rscale5 = alloc(Nn);
    float* rscale6 = alloc(Nn);
    int* deg = (int*)alloc(Nn);
    int* rowptr = (int*)alloc(Nn + 1);
    int* rp5c = (int*)alloc(Nn + 1);
    int* rp6c = (int*)alloc(Nn + 1);
    int* woff = (int*)alloc(Nn);
    int* bsum = (int*)alloc(256);
    int* boff = (int*)alloc(256);
    unsigned int* elist = (unsigned int*)alloc(Ee);
    int* cidx5 = (int*)alloc(N5c * 5);
    int* cidx6 = (int*)alloc(N6c * 6);
    float* ebank = alloc(512 * H);
    __bf16* g1h = allocb(3 * 128 * 256);
    __bf16* g2h = allocb(3 * 256 * 128);
    __bf16* a5h = allocb(3 * 128 * 128);
    __bf16* a6h = allocb(3 * 128 * 128);
    __bf16* c5h = allocb(3 * 128 * 128);
    __bf16* c6h = allocb(3 * 128 * 128);
    __bf16* p5h = allocb(3 * 384 * 128);
    __bf16* p6h = allocb(3 * 384 * 128);

    const int TPB = 256;
    auto cdiv = [](int a, int b) { return (a + b - 1) / b; };
    int nsb = cdiv(Nn, 1024);

    // weight pre-split (transposed bf16 planes)
    k_split<<<cdiv(3 * 128 * 256, TPB), TPB, 0, stream>>>(gw1, g1h, 3, 128, 256);
    k_split<<<cdiv(3 * 256 * 128, TPB), TPB, 0, stream>>>(gw2, g2h, 3, 256, 128);
    k_split<<<cdiv(3 * 128 * 128, TPB), TPB, 0, stream>>>(a2c5_w, a5h, 3, 128, 128);
    k_split<<<cdiv(3 * 128 * 128, TPB), TPB, 0, stream>>>(a2c6_w, a6h, 3, 128, 128);
    k_split<<<cdiv(3 * 128 * 128, TPB), TPB, 0, stream>>>(c2a5_w, c5h, 3, 128, 128);
    k_split<<<cdiv(3 * 128 * 128, TPB), TPB, 0, stream>>>(c2a6_w, c6h, 3, 128, 128);
    k_split<<<cdiv(3 * 384 * 128, TPB), TPB, 0, stream>>>(p5_w, p5h, 3, 384, 128);
    k_split<<<cdiv(3 * 384 * 128, TPB), TPB, 0, stream>>>(p6_w, p6h, 3, 384, 128);

    // edge CSR
    hipMemsetAsync(deg, 0, Nn * 4, stream);
    k_degi<<<cdiv(Ee, TPB), TPB, 0, stream>>>(ei + Ee, deg, Ee);
    k_scan1<<<nsb, 256, 0, stream>>>(deg, rowptr, bsum, Nn);
    k_scan2<<<1, 128, 0, stream>>>(bsum, boff, rowptr, nsb, Nn);
    k_scan3<<<cdiv(Nn, TPB), TPB, 0, stream>>>(rowptr, boff, Nn);
    hipMemcpyAsync(woff, rowptr, Nn * 4, hipMemcpyDeviceToDevice, stream);
    k_fill<<<cdiv(Ee, TPB), TPB, 0, stream>>>(ei, eattr, woff, elist);

    // cycle->atom CSRs + mean scales
    hipMemsetAsync(deg, 0, Nn * 4, stream);
    k_degi<<<cdiv(N5c * 5, TPB), TPB, 0, stream>>>(a2c5_row, deg, N5c * 5);
    k_scan1<<<nsb, 256, 0, stream>>>(deg, rp5c, bsum, Nn);
    k_scan2<<<1, 128, 0, stream>>>(bsum, boff, rp5c, nsb, Nn);
    k_scan3<<<cdiv(Nn, TPB), TPB, 0, stream>>>(rp5c, boff, Nn);
    k_inv_int<<<cdiv(Nn, TPB), TPB, 0, stream>>>(deg, rscale5);
    hipMemcpyAsync(woff, rp5c, Nn * 4, hipMemcpyDeviceToDevice, stream);
    k_fill_idx<<<cdiv(N5c * 5, TPB), TPB, 0, stream>>>(a2c5_row, woff, cidx5, N5c * 5);

    hipMemsetAsync(deg, 0, Nn * 4, stream);
    k_degi<<<cdiv(N6c * 6, TPB), TPB, 0, stream>>>(a2c6_row, deg, N6c * 6);
    k_scan1<<<nsb, 256, 0, stream>>>(deg, rp6c, bsum, Nn);
    k_scan2<<<1, 128, 0, stream>>>(bsum, boff, rp6c, nsb, Nn);
    k_scan3<<<cdiv(Nn, TPB), TPB, 0, stream>>>(rp6c, boff, Nn);
    k_inv_int<<<cdiv(Nn, TPB), TPB, 0, stream>>>(deg, rscale6);
    hipMemcpyAsync(woff, rp6c, Nn * 4, hipMemcpyDeviceToDevice, stream);
    k_fill_idx<<<cdiv(N6c * 6, TPB), TPB, 0, stream>>>(a2c6_row, woff, cidx6, N6c * 6);

    k_atom_enc<<<cdiv(Nn * H, TPB), TPB, 0, stream>>>(x_atom, atom_emb, x);
    k_cyc_init<<<cdiv(N5c * 5 * H, TPB), TPB, 0, stream>>>(xc5, cyc5, x5, N5c * 5);
    k_cyc_init<<<cdiv(N6c * 6 * H, TPB), TPB, 0, stream>>>(xc6, cyc6, x6, N6c * 6);

    for (int i = 0; i < Ll; ++i) {
        // GINE aggregation (gather) -> agg
        k_ebank<<<cdiv(512 * H, TPB), TPB, 0, stream>>>(
            bond_emb + (size_t)i * BF * BV * H, ebank);
        k_agg_csr<<<Nn / 2, 256, 0, stream>>>(x, rowptr, elist, ebank, eps, i, agg);

        // MLP pass A: BN1 stats only
        hipMemsetAsync(stats, 0, 512 * 4, stream);
        k_mlp_statsA<<<cdiv(Nn, 64), 256, 0, stream>>>(
            agg, g1h + (size_t)i * 128 * 256, gb1 + (size_t)i * 256, stats, Nn);

        // MLP fused pass B -> x_raw (pre-BN2) + BN2 stats
        hipMemsetAsync(stats2, 0, 256 * 4, stream);
        k_mlp_fused<<<cdiv(Nn, 64), 256, 0, stream>>>(
            agg, g1h + (size_t)i * 128 * 256, gb1 + (size_t)i * 256, stats,
            gbn_g + (size_t)i * 256, gbn_b + (size_t)i * 256,
            g2h + (size_t)i * 256 * 128, gb2 + (size_t)i * H, x, stats2, Nn);

        // atoms -> cycles (row-gather GEMM with folded BN2+relu on A, in-place res)
        k_mgemm<4><<<cdiv(N5c * 5, 64), 256, 0, stream>>>(
            x, a5h + (size_t)i * 128 * 128, a2c5_b + (size_t)i * H,
            x5, x5, a2c5_row,
            stats2, bn_g + (size_t)i * H, bn_b + (size_t)i * H,
            N5c * 5, 128, 0, 64, 1, 1);
        k_mgemm<4><<<cdiv(N6c * 6, 64), 256, 0, stream>>>(
            x, a6h + (size_t)i * 128 * 128, a2c6_b + (size_t)i * H,
            x6, x6, a2c6_row,
            stats2, bn_g + (size_t)i * H, bn_b + (size_t)i * H,
            N6c * 6, 128, 0, 64, 1, 1);

        // cyclic path blocks: cycle-aligned 60-row tiles, fully in-place
        k_mgemm<12><<<cdiv(N5c * 5, 60), 256, 0, stream>>>(
            x5, p5h + (size_t)i * 384 * 128, p5_b + (size_t)i * H,
            x5, x5, nullptr, nullptr, nullptr, nullptr,
            N5c * 5, 128, 5, 60, 1, 0);
        k_mgemm<12><<<cdiv(N6c * 6, 60), 256, 0, stream>>>(
            x6, p6h + (size_t)i * 384 * 128, p6_b + (size_t)i * H,
            x6, x6, nullptr, nullptr, nullptr, nullptr,
            N6c * 6, 128, 6, 60, 1, 0);

        // cycles -> atoms: pre-gather mean into agg, then plain GEMM
        k_gmean<<<cdiv(Nn * 16, TPB), TPB, 0, stream>>>(x5, rp5c, cidx5, rscale5, agg);
        k_mgemm<4><<<cdiv(Nn, 64), 256, 0, stream>>>(
            agg, c5h + (size_t)i * 128 * 128, c2a5_b + (size_t)i * H,
            x, x, nullptr,
            stats2, bn_g + (size_t)i * H, bn_b + (size_t)i * H,
            Nn, 128, 0, 64, 1, 2);
        k_gmean<<<cdiv(Nn * 16, TPB), TPB, 0, stream>>>(x6, rp6c, cidx6, rscale6, agg);
        k_mgemm<4><<<cdiv(Nn, 64), 256, 0, stream>>>(
            agg, c6h + (size_t)i * 128 * 128, c2a6_b + (size_t)i * H,
            x, x, nullptr, nullptr, nullptr, nullptr,
            Nn, 128, 0, 64, 1, 0);
    }

    // readout
    hipMemsetAsync(xgsum, 0, (size_t)Gg * H * 4, stream);
    hipMemsetAsync(gcnt, 0, (size_t)Gg * 4, stream);
    k_seg_batch<<<cdiv(Nn, 256), H, 0, stream>>>(x, batch, xgsum, gcnt);
    k_head<<<Gg, H, 0, stream>>>(xgsum, gcnt, alw, alb, lw, lb, out);
}

// Round 16
// 1887.692 us; speedup vs baseline: 1.1197x; 1.0406x over previous
//
#include <hip/hip_runtime.h>

#define H 128
#define Nn 100000
#define Ee 250000
#define N5c 20000
#define N6c 30000
#define Gg 512
#define Ll 3
#define AF 9
#define AV 64
#define BF 3
#define BV 8
#define BN_EPS 1e-5f

typedef __bf16 v8bf __attribute__((ext_vector_type(8)));
typedef float v4f __attribute__((ext_vector_type(4)));

// ---------------- init / embedding kernels ----------------

__global__ void k_atom_enc(const int* __restrict__ xa, const float* __restrict__ emb,
                           __bf16* __restrict__ x) {
    int idx = blockIdx.x * blockDim.x + threadIdx.x;
    if (idx >= Nn * H) return;
    int n = idx >> 7, h = idx & 127;
    float s = 0.f;
#pragma unroll
    for (int f = 0; f < AF; ++f) {
        int a = xa[n * AF + f];
        s += emb[(f * AV + a) * H + h];
    }
    x[idx] = (__bf16)s;
}

__global__ void k_cyc_init(const int* __restrict__ xc, const float* __restrict__ emb,
                           __bf16* __restrict__ xo, int M) {
    int idx = blockIdx.x * blockDim.x + threadIdx.x;
    if (idx >= M * H) return;
    int m = idx >> 7, h = idx & 127;
    xo[idx] = (__bf16)emb[xc[m] * H + h];
}

// weight pre-split: (L,K,N) fp32 row-major -> per-layer transposed [n][k] bf16
__global__ void k_split(const float* __restrict__ src, __bf16* __restrict__ dh,
                        int L, int K, int N) {
    int idx = blockIdx.x * blockDim.x + threadIdx.x;
    int tot = L * K * N;
    if (idx >= tot) return;
    int l = idx / (K * N);
    int r = idx - l * (K * N);
    int k = r / N;
    int n = r - k * N;
    size_t d = (size_t)l * K * N + (size_t)n * K + k;
    dh[d] = (__bf16)src[idx];
}

// ---------------- CSR build helpers ----------------

__global__ void k_degi(const int* __restrict__ row, int* __restrict__ deg, int M) {
    int m = blockIdx.x * blockDim.x + threadIdx.x;
    if (m >= M) return;
    atomicAdd(&deg[row[m]], 1);
}

__global__ void k_scan1(const int* __restrict__ deg, int* __restrict__ rp,
                        int* __restrict__ bsum, int n) {
    __shared__ int s[256];
    int tid = threadIdx.x;
    int base = blockIdx.x * 1024 + tid * 4;
    int v0 = (base < n) ? deg[base] : 0;
    int v1 = (base + 1 < n) ? deg[base + 1] : 0;
    int v2 = (base + 2 < n) ? deg[base + 2] : 0;
    int v3 = (base + 3 < n) ? deg[base + 3] : 0;
    int tsum = v0 + v1 + v2 + v3;
    s[tid] = tsum;
    __syncthreads();
    for (int off = 1; off < 256; off <<= 1) {
        int u = (tid >= off) ? s[tid - off] : 0;
        __syncthreads();
        s[tid] += u;
        __syncthreads();
    }
    int exc = s[tid] - tsum;
    if (base < n) rp[base] = exc;
    if (base + 1 < n) rp[base + 1] = exc + v0;
    if (base + 2 < n) rp[base + 2] = exc + v0 + v1;
    if (base + 3 < n) rp[base + 3] = exc + v0 + v1 + v2;
    if (tid == 255) bsum[blockIdx.x] = s[255];
}

__global__ void k_scan2(const int* __restrict__ bsum, int* __restrict__ boff,
                        int* __restrict__ rp, int nb, int n) {
    __shared__ int s[128];
    int tid = threadIdx.x;
    int v = (tid < nb) ? bsum[tid] : 0;
    s[tid] = v;
    __syncthreads();
    for (int off = 1; off < 128; off <<= 1) {
        int u = (tid >= off) ? s[tid - off] : 0;
        __syncthreads();
        s[tid] += u;
        __syncthreads();
    }
    if (tid < nb) boff[tid] = s[tid] - v;
    if (tid == 127) rp[n] = s[127];
}

__global__ void k_scan3(int* __restrict__ rp, const int* __restrict__ boff, int n) {
    int idx = blockIdx.x * blockDim.x + threadIdx.x;
    if (idx < n) rp[idx] += boff[idx >> 10];
}

__global__ void k_fill(const int* __restrict__ ei, const int* __restrict__ eattr,
                       int* __restrict__ woff, unsigned int* __restrict__ elist) {
    int e = blockIdx.x * blockDim.x + threadIdx.x;
    if (e >= Ee) return;
    int src = ei[e], dst = ei[Ee + e];
    int code = eattr[e * BF + 0] * 64 + eattr[e * BF + 1] * 8 + eattr[e * BF + 2];
    int p = atomicAdd(&woff[dst], 1);
    elist[p] = ((unsigned int)code << 17) | (unsigned int)src;
}

__global__ void k_fill_idx(const int* __restrict__ row, int* __restrict__ woff,
                           int* __restrict__ cidx, int M) {
    int m = blockIdx.x * blockDim.x + threadIdx.x;
    if (m >= M) return;
    int p = atomicAdd(&woff[row[m]], 1);
    cidx[p] = m;
}

__global__ void k_inv_int(const int* __restrict__ deg, float* __restrict__ rscale) {
    int r = blockIdx.x * blockDim.x + threadIdx.x;
    if (r >= Nn) return;
    rscale[r] = 1.f / fmaxf((float)deg[r], 1.f);
}

__global__ void k_ebank(const float* __restrict__ bemb, float* __restrict__ ebank) {
    int idx = blockIdx.x * blockDim.x + threadIdx.x;
    if (idx >= 512 * H) return;
    int code = idx >> 7, h = idx & 127;
    int f0 = code >> 6, f1 = (code >> 3) & 7, f2 = code & 7;
    ebank[idx] = bemb[(0 * BV + f0) * H + h] + bemb[(1 * BV + f1) * H + h]
               + bemb[(2 * BV + f2) * H + h];
}

// GINE aggregation, gather form
__global__ __launch_bounds__(256) void k_agg_csr(
    const __bf16* __restrict__ x, const int* __restrict__ rowptr,
    const unsigned int* __restrict__ elist, const float* __restrict__ ebank,
    const float* __restrict__ eps, int layer, __bf16* __restrict__ agg)
{
    int a = blockIdx.x * 2 + (threadIdx.x >> 7);
    int h = threadIdx.x & 127;
    float acc = (1.f + eps[layer]) * (float)x[(size_t)a * H + h];
    int j0 = rowptr[a], j1 = rowptr[a + 1];
    for (int j = j0; j < j1; ++j) {
        unsigned int u = elist[j];
        int src = u & 0x1FFFF;
        int code = u >> 17;
        acc += fmaxf((float)x[(size_t)src * H + h] + ebank[code * H + h], 0.f);
    }
    agg[(size_t)a * H + h] = (__bf16)acc;
}

// ---------------- MFMA GEMM: 64-row blocks, vectorized transpose epilogue ---------
// A-modes: pathk (cyclic conv); rowidx (row gather); grp/gcol/gscale (CSR mean-
// gather, done ONCE at block start); else direct. All A fragments preloaded upfront.

template <int NKT>
__global__ __launch_bounds__(256) void k_mgemm(
    const __bf16* __restrict__ A, const __bf16* __restrict__ Bth,
    const float* __restrict__ bias, const __bf16* __restrict__ res,
    __bf16* __restrict__ out, const int* __restrict__ rowidx,
    const int* __restrict__ grp, const int* __restrict__ gcol,
    const float* __restrict__ gscale,
    const float* __restrict__ bnstats, const float* __restrict__ bng,
    const float* __restrict__ bnb,
    int M, int Ncol, int pathk, int mtile, int relu_flag, int bnmode)
{
    const int K = NKT * 32;
    __shared__ __bf16 smem[2 * 128 * 40];  // B staging; reused as C transpose tile
    __shared__ float scB[128], shB[128];
    auto Bs = reinterpret_cast<__bf16(*)[128][40]>(smem);

    int t = threadIdx.x;
    int m0 = blockIdx.x * mtile;
    int n0 = blockIdx.y * 128;
    int lane = t & 63, q = lane >> 4, lr = lane & 15;
    int w = t >> 6;

    if (bnmode && t < 128) {
        float mean = bnstats[t] * (1.f / (float)Nn);
        float var = bnstats[128 + t] * (1.f / (float)Nn) - mean * mean;
        float s = bng[t] * rsqrtf(var + BN_EPS);
        scB[t] = s;
        shB[t] = bnb[t] - mean * s;
    }

    int rloc = w * 16 + lr;
    int gm = m0 + rloc;
    bool rvalid = (rloc < mtile) && (gm < M);
    v8bf afrag[NKT];
    if (grp) {
        // CSR mean-gather upfront: fp32 accumulate over 0..deg rows
        float a8[NKT][8];
#pragma unroll
        for (int kt = 0; kt < NKT; ++kt)
#pragma unroll
            for (int i = 0; i < 8; ++i) a8[kt][i] = 0.f;
        float sc = 1.f;
        if (rvalid) {
            int j0 = grp[gm], j1 = grp[gm + 1];
            sc = gscale[gm];
            for (int j = j0; j < j1; ++j) {
                const __bf16* rp2 = A + (size_t)gcol[j] * H;
#pragma unroll
                for (int kt = 0; kt < NKT; ++kt) {
                    v8bf g = *(const v8bf*)(rp2 + kt * 32 + q * 8);
#pragma unroll
                    for (int i = 0; i < 8; ++i) a8[kt][i] += (float)g[i];
                }
            }
        }
#pragma unroll
        for (int kt = 0; kt < NKT; ++kt)
#pragma unroll
            for (int i = 0; i < 8; ++i) afrag[kt][i] = (__bf16)(a8[kt][i] * sc);
    } else {
        const __bf16* base = A;
        int cycb = 0, pm = 0;
        if (rvalid) {
            if (pathk) {
                int cyc = gm / pathk;
                cycb = cyc * pathk;
                pm = gm - cycb;
            } else if (rowidx) {
                base = A + (size_t)rowidx[gm] * H;
            } else {
                base = A + (size_t)gm * K;
            }
        }
#pragma unroll
        for (int kt = 0; kt < NKT; ++kt) {
            v8bf hv = {};
            if (rvalid) {
                if (pathk) {
                    int sel = kt >> 2;
                    int pp = pm + sel - 1;
                    if (pp < 0) pp += pathk;
                    if (pp >= pathk) pp -= pathk;
                    hv = *(const v8bf*)(A + (size_t)(cycb + pp) * H +
                                        ((kt * 32) & 127) + q * 8);
                } else {
                    hv = *(const v8bf*)(base + kt * 32 + q * 8);
                }
            }
            afrag[kt] = hv;
        }
    }
    if (bnmode == 1) {
        __syncthreads();
        if (rvalid) {
#pragma unroll
            for (int kt = 0; kt < NKT; ++kt) {
                int kb = kt * 32 + q * 8;
#pragma unroll
                for (int i = 0; i < 8; ++i)
                    afrag[kt][i] =
                        (__bf16)fmaxf((float)afrag[kt][i] * scB[kb + i] + shB[kb + i], 0.f);
            }
        }
    }

    v4f acc[8] = {};
    int bn = t & 127;
    int ks = t >> 7;

    v8bf vb[2][2];
    auto loadBreg = [&](int c) {
#pragma unroll
        for (int s2 = 0; s2 < 2; ++s2) {
            const __bf16* bp = Bth + (size_t)(n0 + bn) * K + (c << 6) + s2 * 32 + ks * 16;
            vb[s2][0] = *(const v8bf*)bp;
            vb[s2][1] = *(const v8bf*)(bp + 8);
        }
    };
    loadBreg(0);
    const int NC = NKT / 2;
#pragma unroll
    for (int c = 0; c < NC; ++c) {
        __syncthreads();
#pragma unroll
        for (int s2 = 0; s2 < 2; ++s2) {
            *(v8bf*)&Bs[s2][bn][ks * 16] = vb[s2][0];
            *(v8bf*)&Bs[s2][bn][ks * 16 + 8] = vb[s2][1];
        }
        __syncthreads();
        if (c + 1 < NC) loadBreg(c + 1);
#pragma unroll
        for (int s = 0; s < 2; ++s) {
            int kt = c * 2 + s;
#pragma unroll
            for (int nt = 0; nt < 8; ++nt) {
                v8bf bh = *(v8bf*)&Bs[s][nt * 16 + lr][q * 8];
                acc[nt] = __builtin_amdgcn_mfma_f32_16x16x32_bf16(
                    afrag[kt], bh, acc[nt], 0, 0, 0);
            }
        }
    }

    __syncthreads();  // MFMA + B-LDS reads done; smem reusable

    float bcol[8];
#pragma unroll
    for (int nt = 0; nt < 8; ++nt) bcol[nt] = bias[n0 + nt * 16 + lr];

    __bf16* Ct = smem;  // [64][136]
#pragma unroll
    for (int nt = 0; nt < 8; ++nt)
#pragma unroll
        for (int reg = 0; reg < 4; ++reg) {
            int row = w * 16 + q * 4 + reg;
            float v = acc[nt][reg] + bcol[nt];
            if (relu_flag) v = fmaxf(v, 0.f);
            Ct[row * 136 + nt * 16 + lr] = (__bf16)v;
        }
    __syncthreads();
    {
        int row = t >> 2;
        int c0 = (t & 3) * 32;
        int rm = m0 + row;
        if (row < mtile && rm < M) {
#pragma unroll
            for (int seg = 0; seg < 4; ++seg) {
                int cc = c0 + seg * 8;
                v8bf cv = *(v8bf*)&Ct[row * 136 + cc];
                if (res) {
                    v8bf rv2 = *(const v8bf*)&res[(size_t)rm * Ncol + n0 + cc];
#pragma unroll
                    for (int i = 0; i < 8; ++i) {
                        float rf = (float)rv2[i];
                        if (bnmode == 2)
                            rf = fmaxf(rf * scB[cc + i] + shB[cc + i], 0.f);
                        cv[i] = (__bf16)((float)cv[i] + rf);
                    }
                }
                *(v8bf*)&out[(size_t)rm * Ncol + n0 + cc] = cv;
            }
        }
    }
}

// ---------------- MLP pass A: BN1 column stats only (no h1 write) ----------------

__global__ __launch_bounds__(256) void k_mlp_statsA(
    const __bf16* __restrict__ agg, const __bf16* __restrict__ g1h,
    const float* __restrict__ gb1, float* __restrict__ stats, int M)
{
    __shared__ __bf16 smem[2 * 128 * 40];
    __shared__ float sS[256], sQ[256];
    auto Bs = reinterpret_cast<__bf16(*)[128][40]>(smem);

    int t = threadIdx.x;
    int m0 = blockIdx.x * 64;
    int lane = t & 63, q = lane >> 4, lr = lane & 15;
    int w = t >> 6;
    sS[t] = 0.f;
    sQ[t] = 0.f;

    int gm = m0 + w * 16 + lr;
    bool rvalid = (gm < M);
    v8bf afrag[4];
#pragma unroll
    for (int kt = 0; kt < 4; ++kt) {
        v8bf hv = {};
        if (rvalid) hv = *(const v8bf*)(agg + (size_t)gm * H + kt * 32 + q * 8);
        afrag[kt] = hv;
    }

    int bn = t & 127;
    int ks = t >> 7;
    v8bf vb[2][2];
    auto loadB = [&](int step) {
        int p = step >> 1, c = step & 1;
        const __bf16* bp = g1h + (size_t)(p * 128 + bn) * 128 + (c << 6) + ks * 16;
#pragma unroll
        for (int s2 = 0; s2 < 2; ++s2) {
            vb[s2][0] = *(const v8bf*)(bp + s2 * 32);
            vb[s2][1] = *(const v8bf*)(bp + s2 * 32 + 8);
        }
    };
    loadB(0);
    for (int p = 0; p < 2; ++p) {
        v4f acc[8] = {};
#pragma unroll
        for (int c = 0; c < 2; ++c) {
            __syncthreads();
#pragma unroll
            for (int s2 = 0; s2 < 2; ++s2) {
                *(v8bf*)&Bs[s2][bn][ks * 16] = vb[s2][0];
                *(v8bf*)&Bs[s2][bn][ks * 16 + 8] = vb[s2][1];
            }
            __syncthreads();
            int step = p * 2 + c;
            if (step < 3) loadB(step + 1);
#pragma unroll
            for (int s = 0; s < 2; ++s) {
                int kt = c * 2 + s;
#pragma unroll
                for (int nt = 0; nt < 8; ++nt) {
                    v8bf bh = *(v8bf*)&Bs[s][nt * 16 + lr][q * 8];
                    acc[nt] = __builtin_amdgcn_mfma_f32_16x16x32_bf16(
                        afrag[kt], bh, acc[nt], 0, 0, 0);
                }
            }
        }
#pragma unroll
        for (int nt = 0; nt < 8; ++nt) {
            int col = p * 128 + nt * 16 + lr;
            float bv = gb1[col];
            float s = 0.f, q2 = 0.f;
#pragma unroll
            for (int reg = 0; reg < 4; ++reg) {
                int rm = m0 + w * 16 + q * 4 + reg;
                if (rm < M) {
                    float v = acc[nt][reg] + bv;
                    s += v;
                    q2 += v * v;
                }
            }
            atomicAdd(&sS[col], s);
            atomicAdd(&sQ[col], q2);
        }
    }
    __syncthreads();
    atomicAdd(&stats[t], sS[t]);
    atomicAdd(&stats[256 + t], sQ[t]);
}

// ---------------- MLP fused pass B (interleaved panels, reduced LDS) --------------
// stage1 panel p -> T in LDS (64x136) -> stage2 k in [p*128,(p+1)*128).

__global__ __launch_bounds__(256) void k_mlp_fused(
    const __bf16* __restrict__ agg, const __bf16* __restrict__ g1h,
    const float* __restrict__ gb1, const float* __restrict__ statsIn,
    const float* __restrict__ gbn_g, const float* __restrict__ gbn_b,
    const __bf16* __restrict__ g2h, const float* __restrict__ gb2,
    __bf16* __restrict__ outx, float* __restrict__ stats2, int M)
{
    __shared__ __bf16 smem[2 * 128 * 40];   // B staging / C transpose
    __shared__ __bf16 Tt[64 * 136];         // T panel tile (bf16)
    __shared__ float scS[256], shS[256];
    __shared__ float sS[128], sQ[128];
    auto Bs = reinterpret_cast<__bf16(*)[128][40]>(smem);

    int t = threadIdx.x;
    int m0 = blockIdx.x * 64;
    int lane = t & 63, q = lane >> 4, lr = lane & 15;
    int w = t >> 6;

    {
        float mean = statsIn[t] * (1.f / (float)Nn);
        float var = statsIn[256 + t] * (1.f / (float)Nn) - mean * mean;
        float s = gbn_g[t] * rsqrtf(var + BN_EPS);
        scS[t] = s;
        shS[t] = (gb1[t] - mean) * s + gbn_b[t];
    }
    if (t < 128) { sS[t] = 0.f; sQ[t] = 0.f; }

    int gm = m0 + w * 16 + lr;
    bool rvalid = (gm < M);
    v8bf afrag[4];
#pragma unroll
    for (int kt = 0; kt < 4; ++kt) {
        v8bf hv = {};
        if (rvalid) hv = *(const v8bf*)(agg + (size_t)gm * H + kt * 32 + q * 8);
        afrag[kt] = hv;
    }

    int bn = t & 127;
    int ks = t >> 7;
    v8bf vb[2][2];
    // B-load schedule: p0: g1(p0,c0),g1(p0,c1),g2(c0),g2(c1); p1: g1(p1,c0),g1(p1,c1),g2(c2),g2(c3)
    auto loadBany = [&](int step) {
        const __bf16* bp;
        int ph = step >> 2, sl = step & 3;
        if (sl < 2) {
            bp = g1h + (size_t)(ph * 128 + bn) * 128 + (sl << 6) + ks * 16;
        } else {
            int c = ph * 2 + (sl - 2);
            bp = g2h + (size_t)bn * 256 + (c << 6) + ks * 16;
        }
#pragma unroll
        for (int s2 = 0; s2 < 2; ++s2) {
            vb[s2][0] = *(const v8bf*)(bp + s2 * 32);
            vb[s2][1] = *(const v8bf*)(bp + s2 * 32 + 8);
        }
    };
    loadBany(0);

    v4f acc2[8] = {};
    for (int p = 0; p < 2; ++p) {
        // ---- stage 1 panel p ----
        v4f acc1[8] = {};
#pragma unroll
        for (int c = 0; c < 2; ++c) {
            __syncthreads();
#pragma unroll
            for (int s2 = 0; s2 < 2; ++s2) {
                *(v8bf*)&Bs[s2][bn][ks * 16] = vb[s2][0];
                *(v8bf*)&Bs[s2][bn][ks * 16 + 8] = vb[s2][1];
            }
            __syncthreads();
            loadBany(p * 4 + c + 1);
#pragma unroll
            for (int s = 0; s < 2; ++s) {
                int kt = c * 2 + s;
#pragma unroll
                for (int nt = 0; nt < 8; ++nt) {
                    v8bf bh = *(v8bf*)&Bs[s][nt * 16 + lr][q * 8];
                    acc1[nt] = __builtin_amdgcn_mfma_f32_16x16x32_bf16(
                        afrag[kt], bh, acc1[nt], 0, 0, 0);
                }
            }
        }
#pragma unroll
        for (int nt = 0; nt < 8; ++nt)
#pragma unroll
            for (int reg = 0; reg < 4; ++reg) {
                int row = w * 16 + q * 4 + reg;
                int col = p * 128 + nt * 16 + lr;
                float v = fmaxf(acc1[nt][reg] * scS[col] + shS[col], 0.f);
                Tt[row * 136 + nt * 16 + lr] = (__bf16)v;
            }
        __syncthreads();  // Tt panel ready
        v8bf a2[4];
#pragma unroll
        for (int kt = 0; kt < 4; ++kt)
            a2[kt] = *(v8bf*)&Tt[(w * 16 + lr) * 136 + kt * 32 + q * 8];

        // ---- stage 2 chunk pair for this panel ----
#pragma unroll
        for (int c = 0; c < 2; ++c) {
            __syncthreads();
#pragma unroll
            for (int s2 = 0; s2 < 2; ++s2) {
                *(v8bf*)&Bs[s2][bn][ks * 16] = vb[s2][0];
                *(v8bf*)&Bs[s2][bn][ks * 16 + 8] = vb[s2][1];
            }
            __syncthreads();
            int step = p * 4 + 2 + c;
            if (step < 7) loadBany(step + 1);
#pragma unroll
            for (int s = 0; s < 2; ++s) {
                int kt = c * 2 + s;
#pragma unroll
                for (int nt = 0; nt < 8; ++nt) {
                    v8bf bh = *(v8bf*)&Bs[s][nt * 16 + lr][q * 8];
                    acc2[nt] = __builtin_amdgcn_mfma_f32_16x16x32_bf16(
                        a2[kt], bh, acc2[nt], 0, 0, 0);
                }
            }
        }
        if (p == 0) __syncthreads();  // Tt reads done before panel-1 overwrite
    }

    __syncthreads();
    float bcol[8];
#pragma unroll
    for (int nt = 0; nt < 8; ++nt) bcol[nt] = gb2[nt * 16 + lr];
#pragma unroll
    for (int nt = 0; nt < 8; ++nt) {
        float s = 0.f, q2 = 0.f;
#pragma unroll
        for (int reg = 0; reg < 4; ++reg) {
            int rm = m0 + w * 16 + q * 4 + reg;
            if (rm < M) {
                float v = acc2[nt][reg] + bcol[nt];
                s += v;
                q2 += v * v;
            }
        }
        atomicAdd(&sS[nt * 16 + lr], s);
        atomicAdd(&sQ[nt * 16 + lr], q2);
    }
    __bf16* Ct = smem;
#pragma unroll
    for (int nt = 0; nt < 8; ++nt)
#pragma unroll
        for (int reg = 0; reg < 4; ++reg) {
            int row = w * 16 + q * 4 + reg;
            Ct[row * 136 + nt * 16 + lr] = (__bf16)(acc2[nt][reg] + bcol[nt]);
        }
    __syncthreads();
    {
        int row = t >> 2;
        int c0 = (t & 3) * 32;
        int rm = m0 + row;
        if (rm < M) {
#pragma unroll
            for (int seg = 0; seg < 4; ++seg) {
                int cc = c0 + seg * 8;
                *(v8bf*)&outx[(size_t)rm * H + cc] = *(v8bf*)&Ct[row * 136 + cc];
            }
        }
        if (t < 128) {
            atomicAdd(&stats2[t], sS[t]);
            atomicAdd(&stats2[128 + t], sQ[t]);
        }
    }
}

// ---------------- readout ----------------

__global__ void k_seg_batch(const __bf16* __restrict__ x, const int* __restrict__ batch,
                            float* __restrict__ xgsum, float* __restrict__ gcnt) {
    int h = threadIdx.x;
    int r0 = blockIdx.x * 256;
    if (r0 >= Nn) return;
    int r1 = min(r0 + 256, Nn);
    int cur = batch[r0];
    float acc = 0.f, c = 0.f;
    for (int r = r0; r < r1; ++r) {
        int b = batch[r];
        if (b != cur) {
            atomicAdd(&xgsum[cur * H + h], acc);
            if (h == 0) atomicAdd(&gcnt[cur], c);
            acc = 0.f;
            c = 0.f;
            cur = b;
        }
        acc += (float)x[(size_t)r * H + h];
        c += 1.f;
    }
    atomicAdd(&xgsum[cur * H + h], acc);
    if (h == 0) atomicAdd(&gcnt[cur], c);
}

__global__ void k_head(const float* __restrict__ xgsum, const float* __restrict__ gcnt,
                       const float* __restrict__ alw, const float* __restrict__ alb,
                       const float* __restrict__ lw, const float* __restrict__ lb,
                       float* __restrict__ out) {
    __shared__ float mean[H];
    __shared__ float red[H];
    int g = blockIdx.x, j = threadIdx.x;
    mean[j] = xgsum[g * H + j] / fmaxf(gcnt[g], 1.f);
    __syncthreads();
    float acc = alb[j];
    for (int k = 0; k < H; ++k) acc += mean[k] * alw[k * H + j];
    acc = fmaxf(acc, 0.f) * lw[j];
    red[j] = acc;
    __syncthreads();
    for (int s = 64; s > 0; s >>= 1) {
        if (j < s) red[j] += red[j + s];
        __syncthreads();
    }
    if (j == 0) out[g] = red[0] + lb[0];
}

// ---------------- host ----------------

extern "C" void kernel_launch(void* const* d_in, const int* in_sizes, int n_in,
                              void* d_out, int out_size, void* d_ws, size_t ws_size,
                              hipStream_t stream) {
    const int* x_atom = (const int*)d_in[0];
    const int* ei = (const int*)d_in[1];
    const int* eattr = (const int*)d_in[2];
    const int* batch = (const int*)d_in[3];
    const int* xc5 = (const int*)d_in[4];
    const int* xc6 = (const int*)d_in[5];
    const int* a2c5_row = (const int*)d_in[6];
    const int* a2c6_row = (const int*)d_in[8];
    const float* atom_emb = (const float*)d_in[10];
    const float* bond_emb = (const float*)d_in[11];
    const float* cyc5 = (const float*)d_in[12];
    const float* cyc6 = (const float*)d_in[13];
    const float* eps = (const float*)d_in[14];
    const float* gw1 = (const float*)d_in[15];
    const float* gb1 = (const float*)d_in[16];
    const float* gbn_g = (const float*)d_in[17];
    const float* gbn_b = (const float*)d_in[18];
    const float* gw2 = (const float*)d_in[19];
    const float* gb2 = (const float*)d_in[20];
    const float* bn_g = (const float*)d_in[21];
    const float* bn_b = (const float*)d_in[22];
    const float* a2c5_w = (const float*)d_in[23];
    const float* a2c5_b = (const float*)d_in[24];
    const float* a2c6_w = (const float*)d_in[25];
    const float* a2c6_b = (const float*)d_in[26];
    const float* c2a5_w = (const float*)d_in[27];
    const float* c2a5_b = (const float*)d_in[28];
    const float* c2a6_w = (const float*)d_in[29];
    const float* c2a6_b = (const float*)d_in[30];
    const float* p5_w = (const float*)d_in[31];
    const float* p5_b = (const float*)d_in[32];
    const float* p6_w = (const float*)d_in[33];
    const float* p6_b = (const float*)d_in[34];
    const float* alw = (const float*)d_in[35];
    const float* alb = (const float*)d_in[36];
    const float* lw = (const float*)d_in[37];
    const float* lb = (const float*)d_in[38];
    float* out = (float*)d_out;

    float* w = (float*)d_ws;
    size_t o = 0;
    auto alloc = [&](size_t nf) {
        float* p = w + o;
        o += (nf + 63) & ~(size_t)63;
        return p;
    };
    auto allocb = [&](size_t nbf) { return (__bf16*)alloc((nbf + 1) / 2); };
    __bf16* x = allocb((size_t)Nn * H);
    __bf16* x5 = allocb((size_t)N5c * 5 * H);
    __bf16* x6 = allocb((size_t)N6c * 6 * H);
    __bf16* agg = allocb((size_t)Nn * H);
    float* stats = alloc(512);
    float* stats2 = alloc(256);
    float* xgsum = alloc((size_t)Gg * H);
    float* gcnt = alloc(Gg);
    float* rscale5 = alloc(Nn);
    float* rscale6 = alloc(Nn);
    int* deg = (int*)alloc(Nn);
    int* rowptr = (int*)alloc(Nn + 1);
    int* rp5c = (int*)alloc(Nn + 1);
    int* rp6c = (int*)alloc(Nn + 1);
    int* woff = (int*)alloc(Nn);
    int* bsum = (int*)alloc(256);
    int* boff = (int*)alloc(256);
    unsigned int* elist = (unsigned int*)alloc(Ee);
    int* cidx5 = (int*)alloc(N5c * 5);
    int* cidx6 = (int*)alloc(N6c * 6);
    float* ebank = alloc(512 * H);
    __bf16* g1h = allocb(3 * 128 * 256);
    __bf16* g2h = allocb(3 * 256 * 128);
    __bf16* a5h = allocb(3 * 128 * 128);
    __bf16* a6h = allocb(3 * 128 * 128);
    __bf16* c5h = allocb(3 * 128 * 128);
    __bf16* c6h = allocb(3 * 128 * 128);
    __bf16* p5h = allocb(3 * 384 * 128);
    __bf16* p6h = allocb(3 * 384 * 128);

    const int TPB = 256;
    auto cdiv = [](int a, int b) { return (a + b - 1) / b; };
    int nsb = cdiv(Nn, 1024);

    // weight pre-split (transposed bf16 planes)
    k_split<<<cdiv(3 * 128 * 256, TPB), TPB, 0, stream>>>(gw1, g1h, 3, 128, 256);
    k_split<<<cdiv(3 * 256 * 128, TPB), TPB, 0, stream>>>(gw2, g2h, 3, 256, 128);
    k_split<<<cdiv(3 * 128 * 128, TPB), TPB, 0, stream>>>(a2c5_w, a5h, 3, 128, 128);
    k_split<<<cdiv(3 * 128 * 128, TPB), TPB, 0, stream>>>(a2c6_w, a6h, 3, 128, 128);
    k_split<<<cdiv(3 * 128 * 128, TPB), TPB, 0, stream>>>(c2a5_w, c5h, 3, 128, 128);
    k_split<<<cdiv(3 * 128 * 128, TPB), TPB, 0, stream>>>(c2a6_w, c6h, 3, 128, 128);
    k_split<<<cdiv(3 * 384 * 128, TPB), TPB, 0, stream>>>(p5_w, p5h, 3, 384, 128);
    k_split<<<cdiv(3 * 384 * 128, TPB), TPB, 0, stream>>>(p6_w, p6h, 3, 384, 128);

    // edge CSR
    hipMemsetAsync(deg, 0, Nn * 4, stream);
    k_degi<<<cdiv(Ee, TPB), TPB, 0, stream>>>(ei + Ee, deg, Ee);
    k_scan1<<<nsb, 256, 0, stream>>>(deg, rowptr, bsum, Nn);
    k_scan2<<<1, 128, 0, stream>>>(bsum, boff, rowptr, nsb, Nn);
    k_scan3<<<cdiv(Nn, TPB), TPB, 0, stream>>>(rowptr, boff, Nn);
    hipMemcpyAsync(woff, rowptr, Nn * 4, hipMemcpyDeviceToDevice, stream);
    k_fill<<<cdiv(Ee, TPB), TPB, 0, stream>>>(ei, eattr, woff, elist);

    // cycle->atom CSRs + mean scales
    hipMemsetAsync(deg, 0, Nn * 4, stream);
    k_degi<<<cdiv(N5c * 5, TPB), TPB, 0, stream>>>(a2c5_row, deg, N5c * 5);
    k_scan1<<<nsb, 256, 0, stream>>>(deg, rp5c, bsum, Nn);
    k_scan2<<<1, 128, 0, stream>>>(bsum, boff, rp5c, nsb, Nn);
    k_scan3<<<cdiv(Nn, TPB), TPB, 0, stream>>>(rp5c, boff, Nn);
    k_inv_int<<<cdiv(Nn, TPB), TPB, 0, stream>>>(deg, rscale5);
    hipMemcpyAsync(woff, rp5c, Nn * 4, hipMemcpyDeviceToDevice, stream);
    k_fill_idx<<<cdiv(N5c * 5, TPB), TPB, 0, stream>>>(a2c5_row, woff, cidx5, N5c * 5);

    hipMemsetAsync(deg, 0, Nn * 4, stream);
    k_degi<<<cdiv(N6c * 6, TPB), TPB, 0, stream>>>(a2c6_row, deg, N6c * 6);
    k_scan1<<<nsb, 256, 0, stream>>>(deg, rp6c, bsum, Nn);
    k_scan2<<<1, 128, 0, stream>>>(bsum, boff, rp6c, nsb, Nn);
    k_scan3<<<cdiv(Nn, TPB), TPB, 0, stream>>>(rp6c, boff, Nn);
    k_inv_int<<<cdiv(Nn, TPB), TPB, 0, stream>>>(deg, rscale6);
    hipMemcpyAsync(woff, rp6c, Nn * 4, hipMemcpyDeviceToDevice, stream);
    k_fill_idx<<<cdiv(N6c * 6, TPB), TPB, 0, stream>>>(a2c6_row, woff, cidx6, N6c * 6);

    k_atom_enc<<<cdiv(Nn * H, TPB), TPB, 0, stream>>>(x_atom, atom_emb, x);
    k_cyc_init<<<cdiv(N5c * 5 * H, TPB), TPB, 0, stream>>>(xc5, cyc5, x5, N5c * 5);
    k_cyc_init<<<cdiv(N6c * 6 * H, TPB), TPB, 0, stream>>>(xc6, cyc6, x6, N6c * 6);

    for (int i = 0; i < Ll; ++i) {
        // GINE aggregation (gather) -> agg
        k_ebank<<<cdiv(512 * H, TPB), TPB, 0, stream>>>(
            bond_emb + (size_t)i * BF * BV * H, ebank);
        k_agg_csr<<<Nn / 2, 256, 0, stream>>>(x, rowptr, elist, ebank, eps, i, agg);

        // MLP pass A: BN1 stats only
        hipMemsetAsync(stats, 0, 512 * 4, stream);
        k_mlp_statsA<<<cdiv(Nn, 64), 256, 0, stream>>>(
            agg, g1h + (size_t)i * 128 * 256, gb1 + (size_t)i * 256, stats, Nn);

        // MLP fused pass B -> x_raw (pre-BN2) + BN2 stats
        hipMemsetAsync(stats2, 0, 256 * 4, stream);
        k_mlp_fused<<<cdiv(Nn, 64), 256, 0, stream>>>(
            agg, g1h + (size_t)i * 128 * 256, gb1 + (size_t)i * 256, stats,
            gbn_g + (size_t)i * 256, gbn_b + (size_t)i * 256,
            g2h + (size_t)i * 256 * 128, gb2 + (size_t)i * H, x, stats2, Nn);

        // atoms -> cycles (row-gather GEMM with folded BN2+relu on A, in-place res)
        k_mgemm<4><<<cdiv(N5c * 5, 64), 256, 0, stream>>>(
            x, a5h + (size_t)i * 128 * 128, a2c5_b + (size_t)i * H,
            x5, x5, a2c5_row, nullptr, nullptr, nullptr,
            stats2, bn_g + (size_t)i * H, bn_b + (size_t)i * H,
            N5c * 5, 128, 0, 64, 1, 1);
        k_mgemm<4><<<cdiv(N6c * 6, 64), 256, 0, stream>>>(
            x, a6h + (size_t)i * 128 * 128, a2c6_b + (size_t)i * H,
            x6, x6, a2c6_row, nullptr, nullptr, nullptr,
            stats2, bn_g + (size_t)i * H, bn_b + (size_t)i * H,
            N6c * 6, 128, 0, 64, 1, 1);

        // cyclic path blocks: cycle-aligned 60-row tiles, fully in-place
        k_mgemm<12><<<cdiv(N5c * 5, 60), 256, 0, stream>>>(
            x5, p5h + (size_t)i * 384 * 128, p5_b + (size_t)i * H,
            x5, x5, nullptr, nullptr, nullptr, nullptr,
            nullptr, nullptr, nullptr,
            N5c * 5, 128, 5, 60, 1, 0);
        k_mgemm<12><<<cdiv(N6c * 6, 60), 256, 0, stream>>>(
            x6, p6h + (size_t)i * 384 * 128, p6_b + (size_t)i * H,
            x6, x6, nullptr, nullptr, nullptr, nullptr,
            nullptr, nullptr, nullptr,
            N6c * 6, 128, 6, 60, 1, 0);

        // cycles -> atoms (CSR mean-gather fused into upfront A preload)
        k_mgemm<4><<<cdiv(Nn, 64), 256, 0, stream>>>(
            x5, c5h + (size_t)i * 128 * 128, c2a5_b + (size_t)i * H,
            x, x, nullptr, rp5c, cidx5, rscale5,
            stats2, bn_g + (size_t)i * H, bn_b + (size_t)i * H,
            Nn, 128, 0, 64, 1, 2);
        k_mgemm<4><<<cdiv(Nn, 64), 256, 0, stream>>>(
            x6, c6h + (size_t)i * 128 * 128, c2a6_b + (size_t)i * H,
            x, x, nullptr, rp6c, cidx6, rscale6,
            nullptr, nullptr, nullptr,
            Nn, 128, 0, 64, 1, 0);
    }

    // readout
    hipMemsetAsync(xgsum, 0, (size_t)Gg * H * 4, stream);
    hipMemsetAsync(gcnt, 0, (size_t)Gg * 4, stream);
    k_seg_batch<<<cdiv(Nn, 256), H, 0, stream>>>(x, batch, xgsum, gcnt);
    k_head<<<Gg, H, 0, stream>>>(xgsum, gcnt, alw, alb, lw, lb, out);
}